// Round 5
// baseline (255.052 us; speedup 1.0000x reference)
//
#include <hip/hip_runtime.h>

#define EMBED 1024
#define SEQL  2048
#define NHEAD 16
#define HDIM  64
#define NBATCH 2
#define MROWS 4096   // NBATCH*SEQL

typedef __attribute__((ext_vector_type(4))) float  f32x4;
typedef __attribute__((ext_vector_type(8))) __bf16 bf16x8;

__device__ __forceinline__ short f2bf(float f){
  union { float f; unsigned u; } x; x.f = f;
  unsigned r = x.u + 0x7fffu + ((x.u >> 16) & 1u);
  return (short)(r >> 16);
}

#define GLDS(gp, lp) __builtin_amdgcn_global_load_lds( \
    (const __attribute__((address_space(1))) void*)(gp), \
    (__attribute__((address_space(3))) void*)(lp), 16, 0, 0)

// ---------------- fp32 -> bf16 convert (x) ----------------
__global__ __launch_bounds__(256) void cvt_kernel(const float* __restrict__ in,
                                                  short* __restrict__ out, int n){
  int i = (blockIdx.x * 256 + threadIdx.x) * 4;
  if (i >= n) return;
  float4 v = *(const float4*)(in + i);
  short4 o; o.x = f2bf(v.x); o.y = f2bf(v.y); o.z = f2bf(v.z); o.w = f2bf(v.w);
  *(short4*)(out + i) = o;
}

// ------- W [K][N] fp32 -> Wt [N][K] bf16, 4 matrices via blockIdx.z -------
__global__ __launch_bounds__(256) void transpose_kernel(const float* __restrict__ W0,
    const float* __restrict__ W1, const float* __restrict__ W2, const float* __restrict__ W3,
    short* __restrict__ WtAll){
  __shared__ float tile[32][33];
  const int z = blockIdx.z;
  const float* W = (z==0)?W0:(z==1)?W1:(z==2)?W2:W3;
  short* Wt = WtAll + z*(EMBED*EMBED);
  const int bx = blockIdx.x*32, by = blockIdx.y*32;
  const int tx = threadIdx.x & 31, ty = threadIdx.x >> 5;
  #pragma unroll
  for (int i=0;i<32;i+=8) tile[ty+i][tx] = W[(by+ty+i)*EMBED + bx+tx];
  __syncthreads();
  #pragma unroll
  for (int i=0;i<32;i+=8) Wt[(bx+ty+i)*EMBED + by+tx] = f2bf(tile[tx][ty+i]);
}

// ---------------- 128x128 bf16 GEMM mainloop (m97 structure) ----------------
__device__ __forceinline__ void gemm_tile_128(const short* __restrict__ A,
    const short* __restrict__ Bt, short* As, short* Bs, int m0, int n0, f32x4 acc[4][4]){
  const int tid  = threadIdx.x;
  const int lane = tid & 63;
  const int wid  = tid >> 6;
  const int wrow = (wid >> 1) * 64, wcol = (wid & 1) * 64;
  const int arow = tid >> 2, acol8 = (tid & 3) * 8;
  const int l15 = lane & 15, lg = lane >> 4;
  for (int k0 = 0; k0 < 1024; k0 += 32){
    __syncthreads();
    GLDS(A  + (m0      + arow) * 1024 + k0 + acol8, As + tid*8);
    GLDS(A  + (m0 + 64 + arow) * 1024 + k0 + acol8, As + 2048 + tid*8);
    GLDS(Bt + (n0      + arow) * 1024 + k0 + acol8, Bs + tid*8);
    GLDS(Bt + (n0 + 64 + arow) * 1024 + k0 + acol8, Bs + 2048 + tid*8);
    __syncthreads();
    bf16x8 a[4], b[4];
    #pragma unroll
    for (int i=0;i<4;++i) a[i] = *(const bf16x8*)(As + (wrow+16*i+l15)*32 + 8*lg);
    #pragma unroll
    for (int j=0;j<4;++j) b[j] = *(const bf16x8*)(Bs + (wcol+16*j+l15)*32 + 8*lg);
    #pragma unroll
    for (int i=0;i<4;++i)
      #pragma unroll
      for (int j=0;j<4;++j)
        acc[i][j] = __builtin_amdgcn_mfma_f32_16x16x32_bf16(a[i], b[j], acc[i][j], 0,0,0);
  }
}

// QKV projections: z=0 -> Q [b,h,s,d] (pre-scaled), z=1 -> K, z=2 -> V^T [b,h,d,s]
__global__ __launch_bounds__(256) void gemm_qkv_kernel(const short* __restrict__ Xb,
    const short* __restrict__ WtAll, short* __restrict__ Q, short* __restrict__ K,
    short* __restrict__ Vt){
  __shared__ short As[4096], Bs[4096];
  const int m0 = blockIdx.x*128, n0 = blockIdx.y*128, z = blockIdx.z;
  const short* Bt = WtAll + z*(EMBED*EMBED);
  f32x4 acc[4][4] = {};
  gemm_tile_128(Xb, Bt, As, Bs, m0, n0, acc);
  const int lane = threadIdx.x & 63;
  const int wid  = threadIdx.x >> 6;
  const int wrow = (wid >> 1) * 64, wcol = (wid & 1) * 64;
  const int l15 = lane & 15, lg = lane >> 4;
  short* out = (z==0) ? Q : (z==1) ? K : Vt;
  // fold softmax scale (1/8) and log2(e) into Q
  const float qscl = (z==0) ? (0.125f * 1.44269504f) : 1.0f;
  #pragma unroll
  for (int i=0;i<4;++i)
    #pragma unroll
    for (int j=0;j<4;++j)
      #pragma unroll
      for (int r=0;r<4;++r){
        int m = m0 + wrow + 16*i + 4*lg + r;
        int n = n0 + wcol + 16*j + l15;
        int bb = m >> 11, srow = m & 2047, hh = n >> 6, d = n & 63;
        short v = f2bf(acc[i][j][r] * qscl);
        if (z < 2) out[(((bb<<4)+hh)*SEQL + srow)*HDIM + d] = v;
        else       out[(((bb<<4)+hh)*HDIM + d)*SEQL + srow] = v;
      }
}

// Output projection: out = Ctx @ W_o + b_o (fp32)
__global__ __launch_bounds__(256) void gemm_out_kernel(const short* __restrict__ Ctx,
    const short* __restrict__ WtO, const float* __restrict__ bias, float* __restrict__ out){
  __shared__ short As[4096], Bs[4096];
  const int m0 = blockIdx.x*128, n0 = blockIdx.y*128;
  f32x4 acc[4][4] = {};
  gemm_tile_128(Ctx, WtO, As, Bs, m0, n0, acc);
  const int lane = threadIdx.x & 63;
  const int wid  = threadIdx.x >> 6;
  const int wrow = (wid >> 1) * 64, wcol = (wid & 1) * 64;
  const int l15 = lane & 15, lg = lane >> 4;
  #pragma unroll
  for (int i=0;i<4;++i)
    #pragma unroll
    for (int j=0;j<4;++j)
      #pragma unroll
      for (int r=0;r<4;++r){
        int m = m0 + wrow + 16*i + 4*lg + r;
        int n = n0 + wcol + 16*j + l15;
        out[m*EMBED + n] = acc[i][j][r] + bias[n];
      }
}

// ------------- causal flash attention v5 (swapped QK^T + split-KV) ----------
// 1024 blocks x 4 waves = 4096 waves (4/SIMD). Wave-PAIR owns a 32-row q
// slice; wave half=0 does kv tiles [0,h0), half=1 does [h0,nt). Private
// (m,l,acc) merged at the end via LDS (flash-decode). Block = slices
// {i, 63-i} x 2 halves = constant 33 tiles. Head h on XCD h%8.
// S^T = mfma(K, Q): lane col = q (l15), rows kv = 4lg+r; softmax in-lane +
// 2 shfl_xor; T13 defer-max skips rescale when tile max <= running max.
__global__ __launch_bounds__(256, 4) void attn_kernel(const short* __restrict__ Q,
    const short* __restrict__ K, const short* __restrict__ Vt, short* __restrict__ Ctx){
  __shared__ short Pl[4*32*64];         // per-wave 32x64 bf16 P tile (16 KB)
  __shared__ float Mg[2*32*64];         // merge: per-pair acc dump (16 KB)
  __shared__ float Ml[2*2*2*2*16];      // [pair][half][g][m|l][row] (1 KB)
  const int tid  = threadIdx.x;
  const int lane = tid & 63;
  const int wid  = tid >> 6;
  const int pair = wid >> 1;            // 0,1: which q slice
  const int half = wid & 1;             // 0,1: which kv half
  // bid -> (xcd, head, slice-block)
  const int bid  = blockIdx.x;          // 0..1023
  const int xcd  = bid & 7;
  const int rest = bid >> 3;            // 0..127
  const int bh   = xcd + 8*(rest >> 5); // head 0..31 (4 heads per XCD)
  const int iblk = rest & 31;           // 0..31
  const int slice = pair ? (63 - iblk) : iblk;
  const int q0w   = slice * 32;

  const short* Qh = Q  + bh*(SEQL*HDIM);
  const short* Kh = K  + bh*(SEQL*HDIM);
  const short* Vh = Vt + bh*(HDIM*SEQL);
  const int l15 = lane & 15, lg = lane >> 4;
  const int lg20 = 20 * lg;
  const int sw = (l15 & 7) << 3;        // P swizzle (row & 7) << 3, row = 16g+l15

  // Q fragments (B-operand): lane col = q row (l15), k-chunks over d
  bf16x8 bq[2][2];
  #pragma unroll
  for (int g=0; g<2; ++g){
    const short* qp = Qh + (q0w + 16*g + l15)*HDIM + 8*lg;
    bq[g][0] = *(const bf16x8*)qp;
    bq[g][1] = *(const bf16x8*)(qp + 32);
  }

  f32x4 acc[2][4];                      // [g][j]: rows q=16g+4lg+r, cols d=16j+l15
  float mrun[2], lrun[2];
  #pragma unroll
  for (int g=0; g<2; ++g){
    mrun[g] = -3e30f; lrun[g] = 0.f;
    #pragma unroll
    for (int j=0; j<4; ++j) acc[g][j] = (f32x4){0.f,0.f,0.f,0.f};
  }

  short* pw = Pl + wid*2048;            // per-wave 32x64 bf16
  const int nt   = (q0w >> 6) + 1;
  const int h0   = (nt + 1) >> 1;
  const int tbeg = half ? h0 : 0;
  const int tend = half ? nt : h0;

  // preload first K tile of this wave's range
  bf16x8 kr[4][2];
  #pragma unroll
  for (int c=0; c<4; ++c){
    const short* kp = Kh + (tbeg*64 + 16*c + l15)*HDIM + 8*lg;
    kr[c][0] = *(const bf16x8*)kp;
    kr[c][1] = *(const bf16x8*)(kp + 32);
  }

  for (int t = tbeg; t < tend; ++t){
    const int kv0 = t*64;
    // S^T: sc[c][g] rows kv=16c+4lg+r, cols q=16g+l15
    f32x4 sc[4][2];
    #pragma unroll
    for (int c=0; c<4; ++c)
      #pragma unroll
      for (int g=0; g<2; ++g){
        f32x4 z = (f32x4){0.f,0.f,0.f,0.f};
        z = __builtin_amdgcn_mfma_f32_16x16x32_bf16(kr[c][0], bq[g][0], z, 0,0,0);
        z = __builtin_amdgcn_mfma_f32_16x16x32_bf16(kr[c][1], bq[g][1], z, 0,0,0);
        sc[c][g] = z;
      }
    // issue V[t] loads (consumed after softmax)
    bf16x8 vr[4][2];
    #pragma unroll
    for (int j=0; j<4; ++j){
      const short* vp = Vh + (16*j + l15)*SEQL + kv0 + 8*lg;
      vr[j][0] = *(const bf16x8*)vp;
      vr[j][1] = *(const bf16x8*)(vp + 32);
    }
    // reload kr with K tile t+1 (WAR; latency hides under softmax)
    if (t + 1 < tend){
      #pragma unroll
      for (int c=0; c<4; ++c){
        const short* kp = Kh + (kv0 + 64 + 16*c + l15)*HDIM + 8*lg;
        kr[c][0] = *(const bf16x8*)kp;
        kr[c][1] = *(const bf16x8*)(kp + 32);
      }
    }
    // causal mask (global last tile only)
    if (t == nt - 1){
      #pragma unroll
      for (int c=0; c<4; ++c)
        #pragma unroll
        for (int g=0; g<2; ++g)
          #pragma unroll
          for (int r=0; r<4; ++r)
            if (kv0 + 16*c + 4*lg + r > q0w + 16*g + l15) sc[c][g][r] = -3e30f;
    }
    // online softmax per q-group; T13 defer-max
    #pragma unroll
    for (int g=0; g<2; ++g){
      float pm = -3e30f;
      #pragma unroll
      for (int c=0; c<4; ++c)
        #pragma unroll
        for (int r=0; r<4; ++r) pm = fmaxf(pm, sc[c][g][r]);
      pm = fmaxf(pm, __shfl_xor(pm, 16));
      pm = fmaxf(pm, __shfl_xor(pm, 32));
      const int resc = !__all(pm <= mrun[g]);
      float mn = mrun[g], ss = 1.0f;
      if (resc){
        mn = fmaxf(mrun[g], pm);
        ss = __builtin_amdgcn_exp2f(mrun[g] - mn);
        mrun[g] = mn;
      }
      float ls = 0.f;
      #pragma unroll
      for (int c=0; c<4; ++c)
        #pragma unroll
        for (int r=0; r<4; ++r){
          float p = __builtin_amdgcn_exp2f(sc[c][g][r] - mn);
          sc[c][g][r] = p;
          ls += p;
        }
      ls += __shfl_xor(ls, 16);
      ls += __shfl_xor(ls, 32);
      if (resc){
        lrun[g] = lrun[g]*ss + ls;
        float srg[4];
        #pragma unroll
        for (int r=0; r<4; ++r) srg[r] = __shfl(ss, lg20 + r);
        #pragma unroll
        for (int j=0; j<4; ++j)
          #pragma unroll
          for (int r=0; r<4; ++r) acc[g][j][r] *= srg[r];
      } else {
        lrun[g] += ls;
      }
    }
    // P -> LDS: lane holds kv=16c+4lg..+3 (contiguous) for row q=16g+l15
    #pragma unroll
    for (int g=0; g<2; ++g)
      #pragma unroll
      for (int c=0; c<4; ++c){
        short4 pk;
        pk.x = f2bf(sc[c][g][0]); pk.y = f2bf(sc[c][g][1]);
        pk.z = f2bf(sc[c][g][2]); pk.w = f2bf(sc[c][g][3]);
        *(short4*)(pw + (16*g + l15)*64 + ((16*c + 4*lg) ^ sw)) = pk;
      }
    // P read as PV A-frags: row q=16g+l15, k-chunk 8lg within 32m
    bf16x8 pa[2][2];
    #pragma unroll
    for (int g=0; g<2; ++g)
      #pragma unroll
      for (int m=0; m<2; ++m)
        pa[g][m] = *(const bf16x8*)(pw + (16*g + l15)*64 + ((32*m + 8*lg) ^ sw));
    // PV: acc[g][j] += P V  (B-operand from V^T rows = d)
    #pragma unroll
    for (int g=0; g<2; ++g)
      #pragma unroll
      for (int j=0; j<4; ++j){
        acc[g][j] = __builtin_amdgcn_mfma_f32_16x16x32_bf16(pa[g][0], vr[j][0], acc[g][j], 0,0,0);
        acc[g][j] = __builtin_amdgcn_mfma_f32_16x16x32_bf16(pa[g][1], vr[j][1], acc[g][j], 0,0,0);
      }
  }

  // ---- split-KV merge ----
  // dump m,l (values uniform across lg; lane group 0 writes rows = l15)
  if (lg == 0){
    #pragma unroll
    for (int g=0; g<2; ++g){
      Ml[((((pair<<1)+half)<<1)+g)*32 + l15]      = mrun[g];
      Ml[((((pair<<1)+half)<<1)+g)*32 + 16 + l15] = lrun[g];
    }
  }
  // wave half=1 dumps acc (lane-contiguous, conflict-free)
  if (half == 1){
    #pragma unroll
    for (int g=0; g<2; ++g)
      #pragma unroll
      for (int j=0; j<4; ++j)
        #pragma unroll
        for (int r=0; r<4; ++r)
          Mg[pair*2048 + ((g*4+j)*4+r)*64 + lane] = acc[g][j][r];
  }
  __syncthreads();
  if (half == 1) return;

  // wave half=0 merges and writes output
  const int bb = bh >> 4, hh = bh & 15;
  #pragma unroll
  for (int g=0; g<2; ++g){
    const float* mlb0 = Ml + ((((pair<<1)+0)<<1)+g)*32;
    const float* mlb1 = Ml + ((((pair<<1)+1)<<1)+g)*32;
    #pragma unroll
    for (int r=0; r<4; ++r){
      int row = 4*lg + r;                      // q row within group
      float m0 = mlb0[row],      m1 = mlb1[row];
      float l0 = mlb0[16 + row], l1 = mlb1[16 + row];
      float ms = fmaxf(m0, m1);
      float s0 = __builtin_amdgcn_exp2f(m0 - ms);
      float s1 = __builtin_amdgcn_exp2f(m1 - ms);
      float rl = __builtin_amdgcn_rcpf(l0*s0 + l1*s1);
      int qg = q0w + 16*g + row;
      #pragma unroll
      for (int j=0; j<4; ++j){
        float a1 = Mg[pair*2048 + ((g*4+j)*4+r)*64 + lane];
        float v  = (acc[g][j][r]*s0 + a1*s1) * rl;
        Ctx[(bb*SEQL + qg)*EMBED + hh*HDIM + 16*j + l15] = f2bf(v);
      }
    }
  }
}

extern "C" void kernel_launch(void* const* d_in, const int* in_sizes, int n_in,
                              void* d_out, int out_size, void* d_ws, size_t ws_size,
                              hipStream_t stream){
  const float* x  = (const float*)d_in[0];
  const float* Wq = (const float*)d_in[1];
  const float* Wk = (const float*)d_in[2];
  const float* Wv = (const float*)d_in[3];
  const float* Wo = (const float*)d_in[4];
  const float* bo = (const float*)d_in[5];
  float* out = (float*)d_out;

  char* ws = (char*)d_ws;
  const size_t MB = 1u << 20;
  short* Xb  = (short*)(ws +  0*MB);  // [4096][1024] bf16 (8 MB)
  short* Wt  = (short*)(ws +  8*MB);  // 4x [1024][1024] bf16 transposed (8 MB)
  short* Q   = (short*)(ws + 16*MB);  // [b,h,s,d] (8 MB)
  short* Kk  = (short*)(ws + 24*MB);  // [b,h,s,d] (8 MB)
  short* Vt  = (short*)(ws + 32*MB);  // [b,h,d,s] (8 MB)
  short* Ctx = (short*)(ws + 40*MB);  // [b,s,e]   (8 MB)

  cvt_kernel<<<4096, 256, 0, stream>>>(x, Xb, MROWS*EMBED);
  transpose_kernel<<<dim3(32,32,4), 256, 0, stream>>>(Wq, Wk, Wv, Wo, Wt);
  gemm_qkv_kernel<<<dim3(32,8,3), 256, 0, stream>>>(Xb, Wt, Q, Kk, Vt);
  attn_kernel<<<1024, 256, 0, stream>>>(Q, Kk, Vt, Ctx);
  gemm_out_kernel<<<dim3(32,8), 256, 0, stream>>>(Ctx, Wt + 3*(EMBED*EMBED), bo, out);
}

// Round 6
// 143.461 us; speedup vs baseline: 1.7778x; 1.7778x over previous
//
#include <hip/hip_runtime.h>

#define EMBED 1024
#define SEQL  2048
#define NHEAD 16
#define HDIM  64
#define NBATCH 2
#define MROWS 4096   // NBATCH*SEQL

typedef __attribute__((ext_vector_type(4))) float  f32x4;
typedef __attribute__((ext_vector_type(8))) __bf16 bf16x8;

__device__ __forceinline__ short f2bf(float f){
  union { float f; unsigned u; } x; x.f = f;
  unsigned r = x.u + 0x7fffu + ((x.u >> 16) & 1u);
  return (short)(r >> 16);
}

#define GLDS(gp, lp) __builtin_amdgcn_global_load_lds( \
    (const __attribute__((address_space(1))) void*)(gp), \
    (__attribute__((address_space(3))) void*)(lp), 16, 0, 0)

// ---------------- fp32 -> bf16 convert (x) ----------------
__global__ __launch_bounds__(256) void cvt_kernel(const float* __restrict__ in,
                                                  short* __restrict__ out, int n){
  int i = (blockIdx.x * 256 + threadIdx.x) * 4;
  if (i >= n) return;
  float4 v = *(const float4*)(in + i);
  short4 o; o.x = f2bf(v.x); o.y = f2bf(v.y); o.z = f2bf(v.z); o.w = f2bf(v.w);
  *(short4*)(out + i) = o;
}

// ------- W [K][N] fp32 -> Wt [N][K] bf16, 4 matrices via blockIdx.z -------
__global__ __launch_bounds__(256) void transpose_kernel(const float* __restrict__ W0,
    const float* __restrict__ W1, const float* __restrict__ W2, const float* __restrict__ W3,
    short* __restrict__ WtAll){
  __shared__ float tile[32][33];
  const int z = blockIdx.z;
  const float* W = (z==0)?W0:(z==1)?W1:(z==2)?W2:W3;
  short* Wt = WtAll + z*(EMBED*EMBED);
  const int bx = blockIdx.x*32, by = blockIdx.y*32;
  const int tx = threadIdx.x & 31, ty = threadIdx.x >> 5;
  #pragma unroll
  for (int i=0;i<32;i+=8) tile[ty+i][tx] = W[(by+ty+i)*EMBED + bx+tx];
  __syncthreads();
  #pragma unroll
  for (int i=0;i<32;i+=8) Wt[(bx+ty+i)*EMBED + by+tx] = f2bf(tile[tx][ty+i]);
}

// ---------------- 128x128 bf16 GEMM mainloop (m97 structure) ----------------
__device__ __forceinline__ void gemm_tile_128(const short* __restrict__ A,
    const short* __restrict__ Bt, short* As, short* Bs, int m0, int n0, f32x4 acc[4][4]){
  const int tid  = threadIdx.x;
  const int lane = tid & 63;
  const int wid  = tid >> 6;
  const int wrow = (wid >> 1) * 64, wcol = (wid & 1) * 64;
  const int arow = tid >> 2, acol8 = (tid & 3) * 8;
  const int l15 = lane & 15, lg = lane >> 4;
  for (int k0 = 0; k0 < 1024; k0 += 32){
    __syncthreads();
    GLDS(A  + (m0      + arow) * 1024 + k0 + acol8, As + tid*8);
    GLDS(A  + (m0 + 64 + arow) * 1024 + k0 + acol8, As + 2048 + tid*8);
    GLDS(Bt + (n0      + arow) * 1024 + k0 + acol8, Bs + tid*8);
    GLDS(Bt + (n0 + 64 + arow) * 1024 + k0 + acol8, Bs + 2048 + tid*8);
    __syncthreads();
    bf16x8 a[4], b[4];
    #pragma unroll
    for (int i=0;i<4;++i) a[i] = *(const bf16x8*)(As + (wrow+16*i+l15)*32 + 8*lg);
    #pragma unroll
    for (int j=0;j<4;++j) b[j] = *(const bf16x8*)(Bs + (wcol+16*j+l15)*32 + 8*lg);
    #pragma unroll
    for (int i=0;i<4;++i)
      #pragma unroll
      for (int j=0;j<4;++j)
        acc[i][j] = __builtin_amdgcn_mfma_f32_16x16x32_bf16(a[i], b[j], acc[i][j], 0,0,0);
  }
}

// QKV projections: z=0 -> Q [b,h,s,d] (pre-scaled), z=1 -> K, z=2 -> V^T [b,h,d,s]
__global__ __launch_bounds__(256) void gemm_qkv_kernel(const short* __restrict__ Xb,
    const short* __restrict__ WtAll, short* __restrict__ Q, short* __restrict__ K,
    short* __restrict__ Vt){
  __shared__ short As[4096], Bs[4096];
  const int m0 = blockIdx.x*128, n0 = blockIdx.y*128, z = blockIdx.z;
  const short* Bt = WtAll + z*(EMBED*EMBED);
  f32x4 acc[4][4] = {};
  gemm_tile_128(Xb, Bt, As, Bs, m0, n0, acc);
  const int lane = threadIdx.x & 63;
  const int wid  = threadIdx.x >> 6;
  const int wrow = (wid >> 1) * 64, wcol = (wid & 1) * 64;
  const int l15 = lane & 15, lg = lane >> 4;
  short* out = (z==0) ? Q : (z==1) ? K : Vt;
  // fold softmax scale (1/8) and log2(e) into Q
  const float qscl = (z==0) ? (0.125f * 1.44269504f) : 1.0f;
  #pragma unroll
  for (int i=0;i<4;++i)
    #pragma unroll
    for (int j=0;j<4;++j)
      #pragma unroll
      for (int r=0;r<4;++r){
        int m = m0 + wrow + 16*i + 4*lg + r;
        int n = n0 + wcol + 16*j + l15;
        int bb = m >> 11, srow = m & 2047, hh = n >> 6, d = n & 63;
        short v = f2bf(acc[i][j][r] * qscl);
        if (z < 2) out[(((bb<<4)+hh)*SEQL + srow)*HDIM + d] = v;
        else       out[(((bb<<4)+hh)*HDIM + d)*SEQL + srow] = v;
      }
}

// Output projection: out = Ctx @ W_o + b_o (fp32)
__global__ __launch_bounds__(256) void gemm_out_kernel(const short* __restrict__ Ctx,
    const short* __restrict__ WtO, const float* __restrict__ bias, float* __restrict__ out){
  __shared__ short As[4096], Bs[4096];
  const int m0 = blockIdx.x*128, n0 = blockIdx.y*128;
  f32x4 acc[4][4] = {};
  gemm_tile_128(Ctx, WtO, As, Bs, m0, n0, acc);
  const int lane = threadIdx.x & 63;
  const int wid  = threadIdx.x >> 6;
  const int wrow = (wid >> 1) * 64, wcol = (wid & 1) * 64;
  const int l15 = lane & 15, lg = lane >> 4;
  #pragma unroll
  for (int i=0;i<4;++i)
    #pragma unroll
    for (int j=0;j<4;++j)
      #pragma unroll
      for (int r=0;r<4;++r){
        int m = m0 + wrow + 16*i + 4*lg + r;
        int n = n0 + wcol + 16*j + l15;
        out[m*EMBED + n] = acc[i][j][r] + bias[n];
      }
}

// ------------- causal flash attention v6 (split-KV, 256-VGPR budget) --------
// Identical structure to v5 but __launch_bounds__(256,2): the v5 (256,4)
// 128-VGPR cap spilled ~150 live VGPRs to scratch (554 MB/dispatch HBM).
// 1024 blocks x 4 waves = 4096 waves. Wave-PAIR owns a 32-row q slice;
// half=0 does kv tiles [0,h0), half=1 does [h0,nt); merged via LDS.
// T5 setprio around MFMA clusters (phase-independent waves).
__global__ __launch_bounds__(256, 2) void attn_kernel(const short* __restrict__ Q,
    const short* __restrict__ K, const short* __restrict__ Vt, short* __restrict__ Ctx){
  __shared__ short Pl[4*32*64];         // per-wave 32x64 bf16 P tile (16 KB)
  __shared__ float Mg[2*32*64];         // merge: per-pair acc dump (16 KB)
  __shared__ float Ml[2*2*2*2*16];      // [pair][half][g][m|l][row] (1 KB)
  const int tid  = threadIdx.x;
  const int lane = tid & 63;
  const int wid  = tid >> 6;
  const int pair = wid >> 1;            // 0,1: which q slice
  const int half = wid & 1;             // 0,1: which kv half
  // bid -> (xcd, head, slice-block)
  const int bid  = blockIdx.x;          // 0..1023
  const int xcd  = bid & 7;
  const int rest = bid >> 3;            // 0..127
  const int bh   = xcd + 8*(rest >> 5); // head 0..31 (4 heads per XCD)
  const int iblk = rest & 31;           // 0..31
  const int slice = pair ? (63 - iblk) : iblk;
  const int q0w   = slice * 32;

  const short* Qh = Q  + bh*(SEQL*HDIM);
  const short* Kh = K  + bh*(SEQL*HDIM);
  const short* Vh = Vt + bh*(HDIM*SEQL);
  const int l15 = lane & 15, lg = lane >> 4;
  const int lg20 = 20 * lg;
  const int sw = (l15 & 7) << 3;        // P swizzle (row & 7) << 3, row = 16g+l15

  // Q fragments (B-operand): lane col = q row (l15), k-chunks over d
  bf16x8 bq[2][2];
  #pragma unroll
  for (int g=0; g<2; ++g){
    const short* qp = Qh + (q0w + 16*g + l15)*HDIM + 8*lg;
    bq[g][0] = *(const bf16x8*)qp;
    bq[g][1] = *(const bf16x8*)(qp + 32);
  }

  f32x4 acc[2][4];                      // [g][j]: rows q=16g+4lg+r, cols d=16j+l15
  float mrun[2], lrun[2];
  #pragma unroll
  for (int g=0; g<2; ++g){
    mrun[g] = -3e30f; lrun[g] = 0.f;
    #pragma unroll
    for (int j=0; j<4; ++j) acc[g][j] = (f32x4){0.f,0.f,0.f,0.f};
  }

  short* pw = Pl + wid*2048;            // per-wave 32x64 bf16
  const int nt   = (q0w >> 6) + 1;
  const int h0   = (nt + 1) >> 1;
  const int tbeg = half ? h0 : 0;
  const int tend = half ? nt : h0;

  // preload first K tile of this wave's range
  bf16x8 kr[4][2];
  #pragma unroll
  for (int c=0; c<4; ++c){
    const short* kp = Kh + (tbeg*64 + 16*c + l15)*HDIM + 8*lg;
    kr[c][0] = *(const bf16x8*)kp;
    kr[c][1] = *(const bf16x8*)(kp + 32);
  }

  for (int t = tbeg; t < tend; ++t){
    const int kv0 = t*64;
    // S^T: sc[c][g] rows kv=16c+4lg+r, cols q=16g+l15
    f32x4 sc[4][2];
    __builtin_amdgcn_s_setprio(1);
    #pragma unroll
    for (int c=0; c<4; ++c)
      #pragma unroll
      for (int g=0; g<2; ++g){
        f32x4 z = (f32x4){0.f,0.f,0.f,0.f};
        z = __builtin_amdgcn_mfma_f32_16x16x32_bf16(kr[c][0], bq[g][0], z, 0,0,0);
        z = __builtin_amdgcn_mfma_f32_16x16x32_bf16(kr[c][1], bq[g][1], z, 0,0,0);
        sc[c][g] = z;
      }
    __builtin_amdgcn_s_setprio(0);
    // issue V[t] loads (consumed after softmax)
    bf16x8 vr[4][2];
    #pragma unroll
    for (int j=0; j<4; ++j){
      const short* vp = Vh + (16*j + l15)*SEQL + kv0 + 8*lg;
      vr[j][0] = *(const bf16x8*)vp;
      vr[j][1] = *(const bf16x8*)(vp + 32);
    }
    // reload kr with K tile t+1 (WAR; latency hides under softmax)
    if (t + 1 < tend){
      #pragma unroll
      for (int c=0; c<4; ++c){
        const short* kp = Kh + (kv0 + 64 + 16*c + l15)*HDIM + 8*lg;
        kr[c][0] = *(const bf16x8*)kp;
        kr[c][1] = *(const bf16x8*)(kp + 32);
      }
    }
    // causal mask (global last tile only)
    if (t == nt - 1){
      #pragma unroll
      for (int c=0; c<4; ++c)
        #pragma unroll
        for (int g=0; g<2; ++g)
          #pragma unroll
          for (int r=0; r<4; ++r)
            if (kv0 + 16*c + 4*lg + r > q0w + 16*g + l15) sc[c][g][r] = -3e30f;
    }
    // online softmax per q-group; T13 defer-max
    #pragma unroll
    for (int g=0; g<2; ++g){
      float pm = -3e30f;
      #pragma unroll
      for (int c=0; c<4; ++c)
        #pragma unroll
        for (int r=0; r<4; ++r) pm = fmaxf(pm, sc[c][g][r]);
      pm = fmaxf(pm, __shfl_xor(pm, 16));
      pm = fmaxf(pm, __shfl_xor(pm, 32));
      const int resc = !__all(pm <= mrun[g]);
      float mn = mrun[g], ss = 1.0f;
      if (resc){
        mn = fmaxf(mrun[g], pm);
        ss = __builtin_amdgcn_exp2f(mrun[g] - mn);
        mrun[g] = mn;
      }
      float ls = 0.f;
      #pragma unroll
      for (int c=0; c<4; ++c)
        #pragma unroll
        for (int r=0; r<4; ++r){
          float p = __builtin_amdgcn_exp2f(sc[c][g][r] - mn);
          sc[c][g][r] = p;
          ls += p;
        }
      ls += __shfl_xor(ls, 16);
      ls += __shfl_xor(ls, 32);
      if (resc){
        lrun[g] = lrun[g]*ss + ls;
        float srg[4];
        #pragma unroll
        for (int r=0; r<4; ++r) srg[r] = __shfl(ss, lg20 + r);
        #pragma unroll
        for (int j=0; j<4; ++j)
          #pragma unroll
          for (int r=0; r<4; ++r) acc[g][j][r] *= srg[r];
      } else {
        lrun[g] += ls;
      }
    }
    // P -> LDS: lane holds kv=16c+4lg..+3 (contiguous) for row q=16g+l15
    #pragma unroll
    for (int g=0; g<2; ++g)
      #pragma unroll
      for (int c=0; c<4; ++c){
        short4 pk;
        pk.x = f2bf(sc[c][g][0]); pk.y = f2bf(sc[c][g][1]);
        pk.z = f2bf(sc[c][g][2]); pk.w = f2bf(sc[c][g][3]);
        *(short4*)(pw + (16*g + l15)*64 + ((16*c + 4*lg) ^ sw)) = pk;
      }
    // P read as PV A-frags: row q=16g+l15, k-chunk 8lg within 32m
    bf16x8 pa[2][2];
    #pragma unroll
    for (int g=0; g<2; ++g)
      #pragma unroll
      for (int m=0; m<2; ++m)
        pa[g][m] = *(const bf16x8*)(pw + (16*g + l15)*64 + ((32*m + 8*lg) ^ sw));
    // PV: acc[g][j] += P V  (B-operand from V^T rows = d)
    __builtin_amdgcn_s_setprio(1);
    #pragma unroll
    for (int g=0; g<2; ++g)
      #pragma unroll
      for (int j=0; j<4; ++j){
        acc[g][j] = __builtin_amdgcn_mfma_f32_16x16x32_bf16(pa[g][0], vr[j][0], acc[g][j], 0,0,0);
        acc[g][j] = __builtin_amdgcn_mfma_f32_16x16x32_bf16(pa[g][1], vr[j][1], acc[g][j], 0,0,0);
      }
    __builtin_amdgcn_s_setprio(0);
  }

  // ---- split-KV merge ----
  // dump m,l (values uniform across lg; lane group 0 writes rows = l15)
  if (lg == 0){
    #pragma unroll
    for (int g=0; g<2; ++g){
      Ml[((((pair<<1)+half)<<1)+g)*32 + l15]      = mrun[g];
      Ml[((((pair<<1)+half)<<1)+g)*32 + 16 + l15] = lrun[g];
    }
  }
  // wave half=1 dumps acc (lane-contiguous, conflict-free)
  if (half == 1){
    #pragma unroll
    for (int g=0; g<2; ++g)
      #pragma unroll
      for (int j=0; j<4; ++j)
        #pragma unroll
        for (int r=0; r<4; ++r)
          Mg[pair*2048 + ((g*4+j)*4+r)*64 + lane] = acc[g][j][r];
  }
  __syncthreads();
  if (half == 1) return;

  // wave half=0 merges and writes output
  const int bb = bh >> 4, hh = bh & 15;
  #pragma unroll
  for (int g=0; g<2; ++g){
    const float* mlb0 = Ml + ((((pair<<1)+0)<<1)+g)*32;
    const float* mlb1 = Ml + ((((pair<<1)+1)<<1)+g)*32;
    #pragma unroll
    for (int r=0; r<4; ++r){
      int row = 4*lg + r;                      // q row within group
      float m0 = mlb0[row],      m1 = mlb1[row];
      float l0 = mlb0[16 + row], l1 = mlb1[16 + row];
      float ms = fmaxf(m0, m1);
      float s0 = __builtin_amdgcn_exp2f(m0 - ms);
      float s1 = __builtin_amdgcn_exp2f(m1 - ms);
      float rl = __builtin_amdgcn_rcpf(l0*s0 + l1*s1);
      int qg = q0w + 16*g + row;
      #pragma unroll
      for (int j=0; j<4; ++j){
        float a1 = Mg[pair*2048 + ((g*4+j)*4+r)*64 + lane];
        float v  = (acc[g][j][r]*s0 + a1*s1) * rl;
        Ctx[(bb*SEQL + qg)*EMBED + hh*HDIM + 16*j + l15] = f2bf(v);
      }
    }
  }
}

extern "C" void kernel_launch(void* const* d_in, const int* in_sizes, int n_in,
                              void* d_out, int out_size, void* d_ws, size_t ws_size,
                              hipStream_t stream){
  const float* x  = (const float*)d_in[0];
  const float* Wq = (const float*)d_in[1];
  const float* Wk = (const float*)d_in[2];
  const float* Wv = (const float*)d_in[3];
  const float* Wo = (const float*)d_in[4];
  const float* bo = (const float*)d_in[5];
  float* out = (float*)d_out;

  char* ws = (char*)d_ws;
  const size_t MB = 1u << 20;
  short* Xb  = (short*)(ws +  0*MB);  // [4096][1024] bf16 (8 MB)
  short* Wt  = (short*)(ws +  8*MB);  // 4x [1024][1024] bf16 transposed (8 MB)
  short* Q   = (short*)(ws + 16*MB);  // [b,h,s,d] (8 MB)
  short* Kk  = (short*)(ws + 24*MB);  // [b,h,s,d] (8 MB)
  short* Vt  = (short*)(ws + 32*MB);  // [b,h,d,s] (8 MB)
  short* Ctx = (short*)(ws + 40*MB);  // [b,s,e]   (8 MB)

  cvt_kernel<<<4096, 256, 0, stream>>>(x, Xb, MROWS*EMBED);
  transpose_kernel<<<dim3(32,32,4), 256, 0, stream>>>(Wq, Wk, Wv, Wo, Wt);
  gemm_qkv_kernel<<<dim3(32,8,3), 256, 0, stream>>>(Xb, Wt, Q, Kk, Vt);
  attn_kernel<<<1024, 256, 0, stream>>>(Q, Kk, Vt, Ctx);
  gemm_out_kernel<<<dim3(32,8), 256, 0, stream>>>(Ctx, Wt + 3*(EMBED*EMBED), bo, out);
}

// Round 7
// 134.884 us; speedup vs baseline: 1.8909x; 1.0636x over previous
//
#include <hip/hip_runtime.h>

#define EMBED 1024
#define SEQL  2048
#define NHEAD 16
#define HDIM  64
#define NBATCH 2
#define MROWS 4096   // NBATCH*SEQL

typedef __attribute__((ext_vector_type(4))) float  f32x4;
typedef __attribute__((ext_vector_type(8))) __bf16 bf16x8;

__device__ __forceinline__ short f2bf(float f){
  union { float f; unsigned u; } x; x.f = f;
  unsigned r = x.u + 0x7fffu + ((x.u >> 16) & 1u);
  return (short)(r >> 16);
}

#define GLDS(gp, lp) __builtin_amdgcn_global_load_lds( \
    (const __attribute__((address_space(1))) void*)(gp), \
    (__attribute__((address_space(3))) void*)(lp), 16, 0, 0)

// ---------------- fp32 -> bf16 convert (x) ----------------
__global__ __launch_bounds__(256) void cvt_kernel(const float* __restrict__ in,
                                                  short* __restrict__ out, int n){
  int i = (blockIdx.x * 256 + threadIdx.x) * 4;
  if (i >= n) return;
  float4 v = *(const float4*)(in + i);
  short4 o; o.x = f2bf(v.x); o.y = f2bf(v.y); o.z = f2bf(v.z); o.w = f2bf(v.w);
  *(short4*)(out + i) = o;
}

// ------- W [K][N] fp32 -> Wt [N][K] bf16, 4 matrices via blockIdx.z -------
__global__ __launch_bounds__(256) void transpose_kernel(const float* __restrict__ W0,
    const float* __restrict__ W1, const float* __restrict__ W2, const float* __restrict__ W3,
    short* __restrict__ WtAll){
  __shared__ float tile[32][33];
  const int z = blockIdx.z;
  const float* W = (z==0)?W0:(z==1)?W1:(z==2)?W2:W3;
  short* Wt = WtAll + z*(EMBED*EMBED);
  const int bx = blockIdx.x*32, by = blockIdx.y*32;
  const int tx = threadIdx.x & 31, ty = threadIdx.x >> 5;
  #pragma unroll
  for (int i=0;i<32;i+=8) tile[ty+i][tx] = W[(by+ty+i)*EMBED + bx+tx];
  __syncthreads();
  #pragma unroll
  for (int i=0;i<32;i+=8) Wt[(bx+ty+i)*EMBED + by+tx] = f2bf(tile[tx][ty+i]);
}

// ---------------- 128x128 bf16 GEMM mainloop (m97 structure) ----------------
__device__ __forceinline__ void gemm_tile_128(const short* __restrict__ A,
    const short* __restrict__ Bt, short* As, short* Bs, int m0, int n0, f32x4 acc[4][4]){
  const int tid  = threadIdx.x;
  const int lane = tid & 63;
  const int wid  = tid >> 6;
  const int wrow = (wid >> 1) * 64, wcol = (wid & 1) * 64;
  const int arow = tid >> 2, acol8 = (tid & 3) * 8;
  const int l15 = lane & 15, lg = lane >> 4;
  for (int k0 = 0; k0 < 1024; k0 += 32){
    __syncthreads();
    GLDS(A  + (m0      + arow) * 1024 + k0 + acol8, As + tid*8);
    GLDS(A  + (m0 + 64 + arow) * 1024 + k0 + acol8, As + 2048 + tid*8);
    GLDS(Bt + (n0      + arow) * 1024 + k0 + acol8, Bs + tid*8);
    GLDS(Bt + (n0 + 64 + arow) * 1024 + k0 + acol8, Bs + 2048 + tid*8);
    __syncthreads();
    bf16x8 a[4], b[4];
    #pragma unroll
    for (int i=0;i<4;++i) a[i] = *(const bf16x8*)(As + (wrow+16*i+l15)*32 + 8*lg);
    #pragma unroll
    for (int j=0;j<4;++j) b[j] = *(const bf16x8*)(Bs + (wcol+16*j+l15)*32 + 8*lg);
    #pragma unroll
    for (int i=0;i<4;++i)
      #pragma unroll
      for (int j=0;j<4;++j)
        acc[i][j] = __builtin_amdgcn_mfma_f32_16x16x32_bf16(a[i], b[j], acc[i][j], 0,0,0);
  }
}

// QKV projections: z=0 -> Q [b,h,s,d] (pre-scaled), z=1 -> K, z=2 -> V^T [b,h,d,s]
__global__ __launch_bounds__(256) void gemm_qkv_kernel(const short* __restrict__ Xb,
    const short* __restrict__ WtAll, short* __restrict__ Q, short* __restrict__ K,
    short* __restrict__ Vt){
  __shared__ short As[4096], Bs[4096];
  const int m0 = blockIdx.x*128, n0 = blockIdx.y*128, z = blockIdx.z;
  const short* Bt = WtAll + z*(EMBED*EMBED);
  f32x4 acc[4][4] = {};
  gemm_tile_128(Xb, Bt, As, Bs, m0, n0, acc);
  const int lane = threadIdx.x & 63;
  const int wid  = threadIdx.x >> 6;
  const int wrow = (wid >> 1) * 64, wcol = (wid & 1) * 64;
  const int l15 = lane & 15, lg = lane >> 4;
  short* out = (z==0) ? Q : (z==1) ? K : Vt;
  // fold softmax scale (1/8) and log2(e) into Q
  const float qscl = (z==0) ? (0.125f * 1.44269504f) : 1.0f;
  #pragma unroll
  for (int i=0;i<4;++i)
    #pragma unroll
    for (int j=0;j<4;++j)
      #pragma unroll
      for (int r=0;r<4;++r){
        int m = m0 + wrow + 16*i + 4*lg + r;
        int n = n0 + wcol + 16*j + l15;
        int bb = m >> 11, srow = m & 2047, hh = n >> 6, d = n & 63;
        short v = f2bf(acc[i][j][r] * qscl);
        if (z < 2) out[(((bb<<4)+hh)*SEQL + srow)*HDIM + d] = v;
        else       out[(((bb<<4)+hh)*HDIM + d)*SEQL + srow] = v;
      }
}

// Output projection: out = Ctx @ W_o + b_o (fp32)
__global__ __launch_bounds__(256) void gemm_out_kernel(const short* __restrict__ Ctx,
    const short* __restrict__ WtO, const float* __restrict__ bias, float* __restrict__ out){
  __shared__ short As[4096], Bs[4096];
  const int m0 = blockIdx.x*128, n0 = blockIdx.y*128;
  f32x4 acc[4][4] = {};
  gemm_tile_128(Ctx, WtO, As, Bs, m0, n0, acc);
  const int lane = threadIdx.x & 63;
  const int wid  = threadIdx.x >> 6;
  const int wrow = (wid >> 1) * 64, wcol = (wid & 1) * 64;
  const int l15 = lane & 15, lg = lane >> 4;
  #pragma unroll
  for (int i=0;i<4;++i)
    #pragma unroll
    for (int j=0;j<4;++j)
      #pragma unroll
      for (int r=0;r<4;++r){
        int m = m0 + wrow + 16*i + 4*lg + r;
        int n = n0 + wcol + 16*j + l15;
        out[m*EMBED + n] = acc[i][j][r] + bias[n];
      }
}

// ------- causal flash attention v7 (block-shared LDS K/V, double-buffered) --
// 512 blocks x 4 waves. Block = 128-row Q chunk of one head; wave w owns rows
// [32w,32w+32). Per KV tile (64): stage K[64x64]+V^T[64x64] (16 KB) into
// LDS[nxt] via global_load_lds with PRE-SWIZZLED global source (rule #21),
// compute from LDS[cur], one __syncthreads per tile. Read swizzle
// byte ^= (row&7)<<4 -> bank-balanced ds_read_b128.
// Swapped QK^T + in-lane softmax + defer-max as v6. Heads on XCD h%8;
// chunk map f(c)=c / 23-c pairs co-resident blocks to constant 36 tiles.
__global__ __launch_bounds__(256, 2) void attn_kernel(const short* __restrict__ Q,
    const short* __restrict__ K, const short* __restrict__ Vt, short* __restrict__ Ctx){
  __shared__ __align__(16) char lds[49152];   // K0 V0 | K1 V1 | P[4 waves]
  const int tid  = threadIdx.x;
  const int lane = tid & 63;
  const int wid  = tid >> 6;
  // bid -> (xcd, head, chunk)
  const int bid   = blockIdx.x;          // 0..511
  const int xcd   = bid & 7;
  const int i7    = bid >> 3;            // 0..63 (per-XCD order)
  const int bh    = xcd + 8*(i7 & 3);    // 4 heads per XCD
  const int cidx  = i7 >> 2;             // 0..15
  const int chunk = (cidx < 8) ? cidx : 23 - cidx;  // pair i,i+32 -> c,15-c
  const int q0blk = chunk * 128;
  const int ntblk = 2*chunk + 2;         // kv tiles for this block
  const int q0w   = q0blk + 32*wid;      // this wave's first q row
  const int qlast = q0w + 31;

  const short* Qh = Q  + bh*(SEQL*HDIM);
  const char*  KhB = (const char*)(K  + bh*(SEQL*HDIM));
  const char*  VhB = (const char*)(Vt + bh*(HDIM*SEQL));
  const int l15 = lane & 15, lg = lane >> 4;
  const int lg20 = 20 * lg;
  const int swE = (l15 & 7) << 3;        // P swizzle (elements)
  const int swB = (l15 & 7) << 4;        // K/V read swizzle (bytes)
  // staging: per-lane pre-swizzled source offsets
  const int laneRow = lane >> 3;                       // 0..7
  const int colSwz  = 16 * ((lane & 7) ^ laneRow);     // inverse swizzle

  // Q fragments (B-operand): lane col = q row (l15), k-chunks over d
  bf16x8 bq[2][2];
  #pragma unroll
  for (int g=0; g<2; ++g){
    const short* qp = Qh + (q0w + 16*g + l15)*HDIM + 8*lg;
    bq[g][0] = *(const bf16x8*)qp;
    bq[g][1] = *(const bf16x8*)(qp + 32);
  }

  f32x4 acc[2][4];                      // [g][j]: rows q=16g+4lg+r, cols d=16j+l15
  float mrun[2], lrun[2];
  #pragma unroll
  for (int g=0; g<2; ++g){
    mrun[g] = -3e30f; lrun[g] = 0.f;
    #pragma unroll
    for (int j=0; j<4; ++j) acc[g][j] = (f32x4){0.f,0.f,0.f,0.f};
  }
  short* pw = (short*)(lds + 32768 + wid*4096);  // per-wave 32x64 bf16 P

  // stage K+V tile t into buffer b (wave stages its 16-row quarter)
  auto STAGE = [&](int b, int t){
    char* kb = lds + b*16384;
    char* vb = kb + 8192;
    const int kv0 = t*64;
    #pragma unroll
    for (int i=0;i<2;++i){
      const int r0 = 16*wid + 8*i;
      GLDS(KhB + (kv0 + r0 + laneRow)*128 + colSwz, kb + r0*128);
      GLDS(VhB + (r0 + laneRow)*4096 + kv0*2 + colSwz, vb + r0*128);
    }
  };

  STAGE(0, 0);
  __syncthreads();

  int cur = 0;
  for (int t = 0; t < ntblk; ++t){
    const int kv0 = t*64;
    if (t + 1 < ntblk) STAGE(cur ^ 1, t + 1);
    if (kv0 <= qlast){
      const char* kb = lds + cur*16384;
      const char* vb = kb + 8192;
      // S^T: sc[c][g] rows kv=16c+4lg+r, cols q=16g+l15 (K from LDS)
      f32x4 sc[4][2];
      __builtin_amdgcn_s_setprio(1);
      #pragma unroll
      for (int c=0; c<4; ++c){
        const char* kr = kb + (16*c + l15)*128;
        bf16x8 k0 = *(const bf16x8*)(kr + ((16*lg) ^ swB));
        bf16x8 k1 = *(const bf16x8*)(kr + ((64 + 16*lg) ^ swB));
        #pragma unroll
        for (int g=0; g<2; ++g){
          f32x4 z = (f32x4){0.f,0.f,0.f,0.f};
          z = __builtin_amdgcn_mfma_f32_16x16x32_bf16(k0, bq[g][0], z, 0,0,0);
          z = __builtin_amdgcn_mfma_f32_16x16x32_bf16(k1, bq[g][1], z, 0,0,0);
          sc[c][g] = z;
        }
      }
      __builtin_amdgcn_s_setprio(0);
      // causal mask (wave-local last tile region)
      if (kv0 + 63 > qlast - 31 + 31){}  // no-op; keep structure simple
      if (kv0 + 63 > q0w){               // tile may cross any row's diagonal
        #pragma unroll
        for (int c=0; c<4; ++c)
          #pragma unroll
          for (int g=0; g<2; ++g)
            #pragma unroll
            for (int r=0; r<4; ++r)
              if (kv0 + 16*c + 4*lg + r > q0w + 16*g + l15) sc[c][g][r] = -3e30f;
      }
      // online softmax per q-group; T13 defer-max
      #pragma unroll
      for (int g=0; g<2; ++g){
        float pm = -3e30f;
        #pragma unroll
        for (int c=0; c<4; ++c)
          #pragma unroll
          for (int r=0; r<4; ++r) pm = fmaxf(pm, sc[c][g][r]);
        pm = fmaxf(pm, __shfl_xor(pm, 16));
        pm = fmaxf(pm, __shfl_xor(pm, 32));
        const int resc = !__all(pm <= mrun[g]);
        float mn = mrun[g], ss = 1.0f;
        if (resc){
          mn = fmaxf(mrun[g], pm);
          ss = __builtin_amdgcn_exp2f(mrun[g] - mn);
          mrun[g] = mn;
        }
        float ls = 0.f;
        #pragma unroll
        for (int c=0; c<4; ++c)
          #pragma unroll
          for (int r=0; r<4; ++r){
            float p = __builtin_amdgcn_exp2f(sc[c][g][r] - mn);
            sc[c][g][r] = p;
            ls += p;
          }
        ls += __shfl_xor(ls, 16);
        ls += __shfl_xor(ls, 32);
        if (resc){
          lrun[g] = lrun[g]*ss + ls;
          float srg[4];
          #pragma unroll
          for (int r=0; r<4; ++r) srg[r] = __shfl(ss, lg20 + r);
          #pragma unroll
          for (int j=0; j<4; ++j)
            #pragma unroll
            for (int r=0; r<4; ++r) acc[g][j][r] *= srg[r];
        } else {
          lrun[g] += ls;
        }
      }
      // P -> per-wave LDS (swizzled), read back as PV A-frags
      #pragma unroll
      for (int g=0; g<2; ++g)
        #pragma unroll
        for (int c=0; c<4; ++c){
          short4 pk;
          pk.x = f2bf(sc[c][g][0]); pk.y = f2bf(sc[c][g][1]);
          pk.z = f2bf(sc[c][g][2]); pk.w = f2bf(sc[c][g][3]);
          *(short4*)(pw + (16*g + l15)*64 + ((16*c + 4*lg) ^ swE)) = pk;
        }
      bf16x8 pa[2][2];
      #pragma unroll
      for (int g=0; g<2; ++g)
        #pragma unroll
        for (int m=0; m<2; ++m)
          pa[g][m] = *(const bf16x8*)(pw + (16*g + l15)*64 + ((32*m + 8*lg) ^ swE));
      // PV: acc[g][j] += P V  (V^T from LDS, rows = d)
      __builtin_amdgcn_s_setprio(1);
      #pragma unroll
      for (int j=0; j<4; ++j){
        const char* vrp = vb + (16*j + l15)*128;
        bf16x8 v0 = *(const bf16x8*)(vrp + ((16*lg) ^ swB));
        bf16x8 v1 = *(const bf16x8*)(vrp + ((64 + 16*lg) ^ swB));
        #pragma unroll
        for (int g=0; g<2; ++g){
          acc[g][j] = __builtin_amdgcn_mfma_f32_16x16x32_bf16(pa[g][0], v0, acc[g][j], 0,0,0);
          acc[g][j] = __builtin_amdgcn_mfma_f32_16x16x32_bf16(pa[g][1], v1, acc[g][j], 0,0,0);
        }
      }
      __builtin_amdgcn_s_setprio(0);
    }
    __syncthreads();
    cur ^= 1;
  }

  // epilogue: redistribute lrun to acc rows, scale, write ctx
  const int bb = bh >> 4, hh = bh & 15;
  #pragma unroll
  for (int g=0; g<2; ++g){
    float lr[4];
    #pragma unroll
    for (int r=0; r<4; ++r) lr[r] = __builtin_amdgcn_rcpf(__shfl(lrun[g], lg20 + r));
    #pragma unroll
    for (int j=0; j<4; ++j)
      #pragma unroll
      for (int r=0; r<4; ++r){
        int qg = q0w + 16*g + 4*lg + r;
        Ctx[(bb*SEQL + qg)*EMBED + hh*HDIM + 16*j + l15] = f2bf(acc[g][j][r] * lr[r]);
      }
  }
}

extern "C" void kernel_launch(void* const* d_in, const int* in_sizes, int n_in,
                              void* d_out, int out_size, void* d_ws, size_t ws_size,
                              hipStream_t stream){
  const float* x  = (const float*)d_in[0];
  const float* Wq = (const float*)d_in[1];
  const float* Wk = (const float*)d_in[2];
  const float* Wv = (const float*)d_in[3];
  const float* Wo = (const float*)d_in[4];
  const float* bo = (const float*)d_in[5];
  float* out = (float*)d_out;

  char* ws = (char*)d_ws;
  const size_t MB = 1u << 20;
  short* Xb  = (short*)(ws +  0*MB);  // [4096][1024] bf16 (8 MB)
  short* Wt  = (short*)(ws +  8*MB);  // 4x [1024][1024] bf16 transposed (8 MB)
  short* Q   = (short*)(ws + 16*MB);  // [b,h,s,d] (8 MB)
  short* Kk  = (short*)(ws + 24*MB);  // [b,h,s,d] (8 MB)
  short* Vt  = (short*)(ws + 32*MB);  // [b,h,d,s] (8 MB)
  short* Ctx = (short*)(ws + 40*MB);  // [b,s,e]   (8 MB)

  cvt_kernel<<<4096, 256, 0, stream>>>(x, Xb, MROWS*EMBED);
  transpose_kernel<<<dim3(32,32,4), 256, 0, stream>>>(Wq, Wk, Wv, Wo, Wt);
  gemm_qkv_kernel<<<dim3(32,8,3), 256, 0, stream>>>(Xb, Wt, Q, Kk, Vt);
  attn_kernel<<<512, 256, 0, stream>>>(Q, Kk, Vt, Ctx);
  gemm_out_kernel<<<dim3(32,8), 256, 0, stream>>>(Ctx, Wt + 3*(EMBED*EMBED), bo, out);
}

// Round 8
// 116.031 us; speedup vs baseline: 2.1981x; 1.1625x over previous
//
#include <hip/hip_runtime.h>

#define EMBED 1024
#define SEQL  2048
#define NHEAD 16
#define HDIM  64
#define NBATCH 2
#define MROWS 4096   // NBATCH*SEQL

typedef __attribute__((ext_vector_type(4))) float  f32x4;
typedef __attribute__((ext_vector_type(8))) __bf16 bf16x8;

__device__ __forceinline__ short f2bf(float f){
  union { float f; unsigned u; } x; x.f = f;
  unsigned r = x.u + 0x7fffu + ((x.u >> 16) & 1u);
  return (short)(r >> 16);
}

#define GLDS(gp, lp) __builtin_amdgcn_global_load_lds( \
    (const __attribute__((address_space(1))) void*)(gp), \
    (__attribute__((address_space(3))) void*)(lp), 16, 0, 0)

// ---------------- fp32 -> bf16 convert (x) ----------------
__global__ __launch_bounds__(256) void cvt_kernel(const float* __restrict__ in,
                                                  short* __restrict__ out, int n){
  int i = (blockIdx.x * 256 + threadIdx.x) * 4;
  if (i >= n) return;
  float4 v = *(const float4*)(in + i);
  short4 o; o.x = f2bf(v.x); o.y = f2bf(v.y); o.z = f2bf(v.z); o.w = f2bf(v.w);
  *(short4*)(out + i) = o;
}

// ------- W [K][N] fp32 -> Wt [N][K] bf16, 4 matrices via blockIdx.z -------
__global__ __launch_bounds__(256) void transpose_kernel(const float* __restrict__ W0,
    const float* __restrict__ W1, const float* __restrict__ W2, const float* __restrict__ W3,
    short* __restrict__ WtAll){
  __shared__ float tile[32][33];
  const int z = blockIdx.z;
  const float* W = (z==0)?W0:(z==1)?W1:(z==2)?W2:W3;
  short* Wt = WtAll + z*(EMBED*EMBED);
  const int bx = blockIdx.x*32, by = blockIdx.y*32;
  const int tx = threadIdx.x & 31, ty = threadIdx.x >> 5;
  #pragma unroll
  for (int i=0;i<32;i+=8) tile[ty+i][tx] = W[(by+ty+i)*EMBED + bx+tx];
  __syncthreads();
  #pragma unroll
  for (int i=0;i<32;i+=8) Wt[(bx+ty+i)*EMBED + by+tx] = f2bf(tile[tx][ty+i]);
}

// ---------------- 128x128 bf16 GEMM mainloop (m97 structure) ----------------
__device__ __forceinline__ void gemm_tile_128(const short* __restrict__ A,
    const short* __restrict__ Bt, short* As, short* Bs, int m0, int n0, f32x4 acc[4][4]){
  const int tid  = threadIdx.x;
  const int lane = tid & 63;
  const int wid  = tid >> 6;
  const int wrow = (wid >> 1) * 64, wcol = (wid & 1) * 64;
  const int arow = tid >> 2, acol8 = (tid & 3) * 8;
  const int l15 = lane & 15, lg = lane >> 4;
  for (int k0 = 0; k0 < 1024; k0 += 32){
    __syncthreads();
    GLDS(A  + (m0      + arow) * 1024 + k0 + acol8, As + tid*8);
    GLDS(A  + (m0 + 64 + arow) * 1024 + k0 + acol8, As + 2048 + tid*8);
    GLDS(Bt + (n0      + arow) * 1024 + k0 + acol8, Bs + tid*8);
    GLDS(Bt + (n0 + 64 + arow) * 1024 + k0 + acol8, Bs + 2048 + tid*8);
    __syncthreads();
    bf16x8 a[4], b[4];
    #pragma unroll
    for (int i=0;i<4;++i) a[i] = *(const bf16x8*)(As + (wrow+16*i+l15)*32 + 8*lg);
    #pragma unroll
    for (int j=0;j<4;++j) b[j] = *(const bf16x8*)(Bs + (wcol+16*j+l15)*32 + 8*lg);
    #pragma unroll
    for (int i=0;i<4;++i)
      #pragma unroll
      for (int j=0;j<4;++j)
        acc[i][j] = __builtin_amdgcn_mfma_f32_16x16x32_bf16(a[i], b[j], acc[i][j], 0,0,0);
  }
}

// QKV projections: z=0 -> Q [b,h,s,d] (pre-scaled), z=1 -> K, z=2 -> V^T [b,h,d,s]
__global__ __launch_bounds__(256) void gemm_qkv_kernel(const short* __restrict__ Xb,
    const short* __restrict__ WtAll, short* __restrict__ Q, short* __restrict__ K,
    short* __restrict__ Vt){
  __shared__ short As[4096], Bs[4096];
  const int m0 = blockIdx.x*128, n0 = blockIdx.y*128, z = blockIdx.z;
  const short* Bt = WtAll + z*(EMBED*EMBED);
  f32x4 acc[4][4] = {};
  gemm_tile_128(Xb, Bt, As, Bs, m0, n0, acc);
  const int lane = threadIdx.x & 63;
  const int wid  = threadIdx.x >> 6;
  const int wrow = (wid >> 1) * 64, wcol = (wid & 1) * 64;
  const int l15 = lane & 15, lg = lane >> 4;
  short* out = (z==0) ? Q : (z==1) ? K : Vt;
  // fold softmax scale (1/8) and log2(e) into Q
  const float qscl = (z==0) ? (0.125f * 1.44269504f) : 1.0f;
  #pragma unroll
  for (int i=0;i<4;++i)
    #pragma unroll
    for (int j=0;j<4;++j)
      #pragma unroll
      for (int r=0;r<4;++r){
        int m = m0 + wrow + 16*i + 4*lg + r;
        int n = n0 + wcol + 16*j + l15;
        int bb = m >> 11, srow = m & 2047, hh = n >> 6, d = n & 63;
        short v = f2bf(acc[i][j][r] * qscl);
        if (z < 2) out[(((bb<<4)+hh)*SEQL + srow)*HDIM + d] = v;
        else       out[(((bb<<4)+hh)*HDIM + d)*SEQL + srow] = v;
      }
}

// Output projection: out = Ctx @ W_o + b_o (fp32)
__global__ __launch_bounds__(256) void gemm_out_kernel(const short* __restrict__ Ctx,
    const short* __restrict__ WtO, const float* __restrict__ bias, float* __restrict__ out){
  __shared__ short As[4096], Bs[4096];
  const int m0 = blockIdx.x*128, n0 = blockIdx.y*128;
  f32x4 acc[4][4] = {};
  gemm_tile_128(Ctx, WtO, As, Bs, m0, n0, acc);
  const int lane = threadIdx.x & 63;
  const int wid  = threadIdx.x >> 6;
  const int wrow = (wid >> 1) * 64, wcol = (wid & 1) * 64;
  const int l15 = lane & 15, lg = lane >> 4;
  #pragma unroll
  for (int i=0;i<4;++i)
    #pragma unroll
    for (int j=0;j<4;++j)
      #pragma unroll
      for (int r=0;r<4;++r){
        int m = m0 + wrow + 16*i + 4*lg + r;
        int n = n0 + wcol + 16*j + l15;
        out[m*EMBED + n] = acc[i][j][r] + bias[n];
      }
}

// --- causal flash attention v8: 8 waves/block, shared LDS K/V, 4 waves/SIMD -
// 512 blocks x 8 waves (512 thr). Block = 128-row Q chunk; wave w owns rows
// [16w,16w+16). Per KV tile (64): block stages K[64x64]+V^T[64x64] (16 KB)
// into LDS[nxt] (global_load_lds, pre-swizzled source), computes from
// LDS[cur], one __syncthreads per tile. 4096 waves total = 4/SIMD supply;
// ~70 VGPR under the (512,4) 128-cap -> 2 blocks/CU (LDS 48 KB).
// Swapped QK^T, in-lane softmax + defer-max, setprio on MFMA clusters.
__global__ __launch_bounds__(512, 4) void attn_kernel(const short* __restrict__ Q,
    const short* __restrict__ K, const short* __restrict__ Vt, short* __restrict__ Ctx){
  __shared__ __align__(16) char lds[49152];   // K0 V0 | K1 V1 | P[8 waves]
  const int tid  = threadIdx.x;
  const int lane = tid & 63;
  const int wid  = tid >> 6;             // 0..7
  // bid -> (xcd, head, chunk)
  const int bid   = blockIdx.x;          // 0..511
  const int xcd   = bid & 7;
  const int i7    = bid >> 3;            // 0..63 (per-XCD order)
  const int bh    = xcd + 8*(i7 & 3);    // 4 heads per XCD
  const int cidx  = i7 >> 2;             // 0..15
  const int chunk = (cidx < 8) ? cidx : 23 - cidx;  // pair sums 15 -> equal work
  const int q0blk = chunk * 128;
  const int ntblk = 2*chunk + 2;         // kv tiles for this block
  const int q0w   = q0blk + 16*wid;      // this wave's first q row
  const int qlast = q0w + 15;

  const short* Qh  = Q  + bh*(SEQL*HDIM);
  const char*  KhB = (const char*)(K  + bh*(SEQL*HDIM));
  const char*  VhB = (const char*)(Vt + bh*(HDIM*SEQL));
  const int l15 = lane & 15, lg = lane >> 4;
  const int lg20 = 20 * lg;
  const int swE = (l15 & 7) << 3;        // P swizzle (elements)
  const int swB = (l15 & 7) << 4;        // K/V read swizzle (bytes)
  // staging: per-lane pre-swizzled source offsets (8 rows/wave, 1 GLDS each)
  const int laneRow = lane >> 3;                       // 0..7
  const int colSwz  = 16 * ((lane & 7) ^ laneRow);     // inverse swizzle
  const int r0 = 8 * wid;                              // this wave's stage rows

  // Q fragments (B-operand): lane col = q row (l15), k-chunks over d
  const short* qp = Qh + (q0w + l15)*HDIM + 8*lg;
  bf16x8 bq0 = *(const bf16x8*)qp;
  bf16x8 bq1 = *(const bf16x8*)(qp + 32);

  f32x4 acc[4];                          // [j]: rows q=4lg+r, cols d=16j+l15
  #pragma unroll
  for (int j=0; j<4; ++j) acc[j] = (f32x4){0.f,0.f,0.f,0.f};
  float mrun = -3e30f, lrun = 0.f;       // per lane: state of q-row l15

  short* pw = (short*)(lds + 32768 + wid*2048);  // per-wave 16x64 bf16 P

  // stage K+V tile t into buffer b (each wave stages 8 K rows + 8 V rows)
  auto STAGE = [&](int b, int t){
    char* kb = lds + b*16384;
    char* vb = kb + 8192;
    const int kv0 = t*64;
    GLDS(KhB + (kv0 + r0 + laneRow)*128 + colSwz, kb + r0*128);
    GLDS(VhB + (r0 + laneRow)*4096 + kv0*2 + colSwz, vb + r0*128);
  };

  STAGE(0, 0);
  __syncthreads();

  int cur = 0;
  for (int t = 0; t < ntblk; ++t){
    const int kv0 = t*64;
    if (t + 1 < ntblk) STAGE(cur ^ 1, t + 1);
    if (kv0 <= qlast){
      const char* kb = lds + cur*16384;
      const char* vb = kb + 8192;
      // S^T: sc[c] rows kv=16c+4lg+r, col q=l15 (K from LDS)
      f32x4 sc[4];
      __builtin_amdgcn_s_setprio(1);
      #pragma unroll
      for (int c=0; c<4; ++c){
        const char* kr = kb + (16*c + l15)*128;
        bf16x8 k0 = *(const bf16x8*)(kr + ((16*lg) ^ swB));
        bf16x8 k1 = *(const bf16x8*)(kr + ((64 + 16*lg) ^ swB));
        f32x4 z = (f32x4){0.f,0.f,0.f,0.f};
        z = __builtin_amdgcn_mfma_f32_16x16x32_bf16(k0, bq0, z, 0,0,0);
        z = __builtin_amdgcn_mfma_f32_16x16x32_bf16(k1, bq1, z, 0,0,0);
        sc[c] = z;
      }
      __builtin_amdgcn_s_setprio(0);
      // causal mask: kv = kv0+16c+4lg+r vs q = q0w+l15
      if (kv0 + 63 > q0w){
        #pragma unroll
        for (int c=0; c<4; ++c)
          #pragma unroll
          for (int r=0; r<4; ++r)
            if (kv0 + 16*c + 4*lg + r > q0w + l15) sc[c][r] = -3e30f;
      }
      // online softmax: in-lane over 16 + 2 shuffles; T13 defer-max
      float pm = -3e30f;
      #pragma unroll
      for (int c=0; c<4; ++c)
        #pragma unroll
        for (int r=0; r<4; ++r) pm = fmaxf(pm, sc[c][r]);
      pm = fmaxf(pm, __shfl_xor(pm, 16));
      pm = fmaxf(pm, __shfl_xor(pm, 32));
      const int resc = !__all(pm <= mrun);
      float mn = mrun, ss = 1.0f;
      if (resc){
        mn = fmaxf(mrun, pm);
        ss = __builtin_amdgcn_exp2f(mrun - mn);
        mrun = mn;
      }
      float ls = 0.f;
      #pragma unroll
      for (int c=0; c<4; ++c)
        #pragma unroll
        for (int r=0; r<4; ++r){
          float p = __builtin_amdgcn_exp2f(sc[c][r] - mn);
          sc[c][r] = p;
          ls += p;
        }
      ls += __shfl_xor(ls, 16);
      ls += __shfl_xor(ls, 32);
      if (resc){
        lrun = lrun*ss + ls;
        float srg[4];
        #pragma unroll
        for (int r=0; r<4; ++r) srg[r] = __shfl(ss, lg20 + r);
        #pragma unroll
        for (int j=0; j<4; ++j)
          #pragma unroll
          for (int r=0; r<4; ++r) acc[j][r] *= srg[r];
      } else {
        lrun += ls;
      }
      // P -> per-wave LDS (swizzled), read back as PV A-frags
      #pragma unroll
      for (int c=0; c<4; ++c){
        short4 pk;
        pk.x = f2bf(sc[c][0]); pk.y = f2bf(sc[c][1]);
        pk.z = f2bf(sc[c][2]); pk.w = f2bf(sc[c][3]);
        *(short4*)(pw + l15*64 + ((16*c + 4*lg) ^ swE)) = pk;
      }
      bf16x8 pa0 = *(const bf16x8*)(pw + l15*64 + ((8*lg)      ^ swE));
      bf16x8 pa1 = *(const bf16x8*)(pw + l15*64 + ((32 + 8*lg) ^ swE));
      // PV: acc[j] += P V  (V^T from LDS, rows = d)
      __builtin_amdgcn_s_setprio(1);
      #pragma unroll
      for (int j=0; j<4; ++j){
        const char* vrp = vb + (16*j + l15)*128;
        bf16x8 v0 = *(const bf16x8*)(vrp + ((16*lg) ^ swB));
        bf16x8 v1 = *(const bf16x8*)(vrp + ((64 + 16*lg) ^ swB));
        acc[j] = __builtin_amdgcn_mfma_f32_16x16x32_bf16(pa0, v0, acc[j], 0,0,0);
        acc[j] = __builtin_amdgcn_mfma_f32_16x16x32_bf16(pa1, v1, acc[j], 0,0,0);
      }
      __builtin_amdgcn_s_setprio(0);
    }
    __syncthreads();
    cur ^= 1;
  }

  // epilogue: redistribute lrun to acc rows, scale, write ctx
  const int bb = bh >> 4, hh = bh & 15;
  float lr[4];
  #pragma unroll
  for (int r=0; r<4; ++r) lr[r] = __builtin_amdgcn_rcpf(__shfl(lrun, lg20 + r));
  #pragma unroll
  for (int j=0; j<4; ++j)
    #pragma unroll
    for (int r=0; r<4; ++r){
      int qg = q0w + 4*lg + r;
      Ctx[(bb*SEQL + qg)*EMBED + hh*HDIM + 16*j + l15] = f2bf(acc[j][r] * lr[r]);
    }
}

extern "C" void kernel_launch(void* const* d_in, const int* in_sizes, int n_in,
                              void* d_out, int out_size, void* d_ws, size_t ws_size,
                              hipStream_t stream){
  const float* x  = (const float*)d_in[0];
  const float* Wq = (const float*)d_in[1];
  const float* Wk = (const float*)d_in[2];
  const float* Wv = (const float*)d_in[3];
  const float* Wo = (const float*)d_in[4];
  const float* bo = (const float*)d_in[5];
  float* out = (float*)d_out;

  char* ws = (char*)d_ws;
  const size_t MB = 1u << 20;
  short* Xb  = (short*)(ws +  0*MB);  // [4096][1024] bf16 (8 MB)
  short* Wt  = (short*)(ws +  8*MB);  // 4x [1024][1024] bf16 transposed (8 MB)
  short* Q   = (short*)(ws + 16*MB);  // [b,h,s,d] (8 MB)
  short* Kk  = (short*)(ws + 24*MB);  // [b,h,s,d] (8 MB)
  short* Vt  = (short*)(ws + 32*MB);  // [b,h,d,s] (8 MB)
  short* Ctx = (short*)(ws + 40*MB);  // [b,s,e]   (8 MB)

  cvt_kernel<<<4096, 256, 0, stream>>>(x, Xb, MROWS*EMBED);
  transpose_kernel<<<dim3(32,32,4), 256, 0, stream>>>(Wq, Wk, Wv, Wo, Wt);
  gemm_qkv_kernel<<<dim3(32,8,3), 256, 0, stream>>>(Xb, Wt, Q, Kk, Vt);
  attn_kernel<<<512, 512, 0, stream>>>(Q, Kk, Vt, Ctx);
  gemm_out_kernel<<<dim3(32,8), 256, 0, stream>>>(Ctx, Wt + 3*(EMBED*EMBED), bo, out);
}

// Round 9
// 113.142 us; speedup vs baseline: 2.2543x; 1.0255x over previous
//
#include <hip/hip_runtime.h>

#define EMBED 1024
#define SEQL  2048
#define NHEAD 16
#define HDIM  64
#define NBATCH 2
#define MROWS 4096   // NBATCH*SEQL

typedef __attribute__((ext_vector_type(4))) float  f32x4;
typedef __attribute__((ext_vector_type(8))) __bf16 bf16x8;

__device__ __forceinline__ short f2bf(float f){
  union { float f; unsigned u; } x; x.f = f;
  unsigned r = x.u + 0x7fffu + ((x.u >> 16) & 1u);
  return (short)(r >> 16);
}

#define GLDS(gp, lp) __builtin_amdgcn_global_load_lds( \
    (const __attribute__((address_space(1))) void*)(gp), \
    (__attribute__((address_space(3))) void*)(lp), 16, 0, 0)

// ---------------- fp32 -> bf16 convert (x) ----------------
__global__ __launch_bounds__(256) void cvt_kernel(const float* __restrict__ in,
                                                  short* __restrict__ out, int n){
  int i = (blockIdx.x * 256 + threadIdx.x) * 4;
  if (i >= n) return;
  float4 v = *(const float4*)(in + i);
  short4 o; o.x = f2bf(v.x); o.y = f2bf(v.y); o.z = f2bf(v.z); o.w = f2bf(v.w);
  *(short4*)(out + i) = o;
}

// ------- W [K][N] fp32 -> Wt [N][K] bf16, 4 matrices via blockIdx.z -------
__global__ __launch_bounds__(256) void transpose_kernel(const float* __restrict__ W0,
    const float* __restrict__ W1, const float* __restrict__ W2, const float* __restrict__ W3,
    short* __restrict__ WtAll){
  __shared__ float tile[32][33];
  const int z = blockIdx.z;
  const float* W = (z==0)?W0:(z==1)?W1:(z==2)?W2:W3;
  short* Wt = WtAll + z*(EMBED*EMBED);
  const int bx = blockIdx.x*32, by = blockIdx.y*32;
  const int tx = threadIdx.x & 31, ty = threadIdx.x >> 5;
  #pragma unroll
  for (int i=0;i<32;i+=8) tile[ty+i][tx] = W[(by+ty+i)*EMBED + bx+tx];
  __syncthreads();
  #pragma unroll
  for (int i=0;i<32;i+=8) Wt[(bx+ty+i)*EMBED + by+tx] = f2bf(tile[tx][ty+i]);
}

// -------- 128x128 bf16 GEMM mainloop, 2-phase double-buffered (T3 min) ------
// Stage k+1 into buf^1 BEFORE computing buf[cur]; ONE __syncthreads per
// K-step (its implicit vmcnt(0) drains the in-flight GLDS after the MFMAs).
// As/Bs: 2 buffers x 4096 shorts each (32 KB total).
__device__ __forceinline__ void gemm_tile_128(const short* __restrict__ A,
    const short* __restrict__ Bt, short* As, short* Bs, int m0, int n0, f32x4 acc[4][4]){
  const int tid  = threadIdx.x;
  const int lane = tid & 63;
  const int wid  = tid >> 6;
  const int wrow = (wid >> 1) * 64, wcol = (wid & 1) * 64;
  const int arow = tid >> 2, acol8 = (tid & 3) * 8;
  const int l15 = lane & 15, lg = lane >> 4;

  auto STAGE = [&](int b, int k0){
    short* as = As + b*4096;
    short* bs = Bs + b*4096;
    GLDS(A  + (m0      + arow) * 1024 + k0 + acol8, as + tid*8);
    GLDS(A  + (m0 + 64 + arow) * 1024 + k0 + acol8, as + 2048 + tid*8);
    GLDS(Bt + (n0      + arow) * 1024 + k0 + acol8, bs + tid*8);
    GLDS(Bt + (n0 + 64 + arow) * 1024 + k0 + acol8, bs + 2048 + tid*8);
  };

  STAGE(0, 0);
  __syncthreads();                      // vmcnt(0) + barrier: buf0 ready
  int cur = 0;
  for (int k0 = 0; k0 < 1024; k0 += 32){
    if (k0 + 32 < 1024) STAGE(cur ^ 1, k0 + 32);   // prefetch next K-tile
    const short* as = As + cur*4096;
    const short* bs = Bs + cur*4096;
    bf16x8 a[4], b[4];
    #pragma unroll
    for (int i=0;i<4;++i) a[i] = *(const bf16x8*)(as + (wrow+16*i+l15)*32 + 8*lg);
    #pragma unroll
    for (int j=0;j<4;++j) b[j] = *(const bf16x8*)(bs + (wcol+16*j+l15)*32 + 8*lg);
    #pragma unroll
    for (int i=0;i<4;++i)
      #pragma unroll
      for (int j=0;j<4;++j)
        acc[i][j] = __builtin_amdgcn_mfma_f32_16x16x32_bf16(a[i], b[j], acc[i][j], 0,0,0);
    __syncthreads();                    // drains prefetch GLDS + LDS reads
    cur ^= 1;
  }
}

// QKV projections: z=0 -> Q [b,h,s,d] (pre-scaled), z=1 -> K, z=2 -> V^T [b,h,d,s]
__global__ __launch_bounds__(256) void gemm_qkv_kernel(const short* __restrict__ Xb,
    const short* __restrict__ WtAll, short* __restrict__ Q, short* __restrict__ K,
    short* __restrict__ Vt){
  __shared__ short As[2*4096], Bs[2*4096];
  const int m0 = blockIdx.x*128, n0 = blockIdx.y*128, z = blockIdx.z;
  const short* Bt = WtAll + z*(EMBED*EMBED);
  f32x4 acc[4][4] = {};
  gemm_tile_128(Xb, Bt, As, Bs, m0, n0, acc);
  const int lane = threadIdx.x & 63;
  const int wid  = threadIdx.x >> 6;
  const int wrow = (wid >> 1) * 64, wcol = (wid & 1) * 64;
  const int l15 = lane & 15, lg = lane >> 4;
  short* out = (z==0) ? Q : (z==1) ? K : Vt;
  // fold softmax scale (1/8) and log2(e) into Q
  const float qscl = (z==0) ? (0.125f * 1.44269504f) : 1.0f;
  #pragma unroll
  for (int i=0;i<4;++i)
    #pragma unroll
    for (int j=0;j<4;++j)
      #pragma unroll
      for (int r=0;r<4;++r){
        int m = m0 + wrow + 16*i + 4*lg + r;
        int n = n0 + wcol + 16*j + l15;
        int bb = m >> 11, srow = m & 2047, hh = n >> 6, d = n & 63;
        short v = f2bf(acc[i][j][r] * qscl);
        if (z < 2) out[(((bb<<4)+hh)*SEQL + srow)*HDIM + d] = v;
        else       out[(((bb<<4)+hh)*HDIM + d)*SEQL + srow] = v;
      }
}

// Output projection: out = Ctx @ W_o + b_o (fp32)
__global__ __launch_bounds__(256) void gemm_out_kernel(const short* __restrict__ Ctx,
    const short* __restrict__ WtO, const float* __restrict__ bias, float* __restrict__ out){
  __shared__ short As[2*4096], Bs[2*4096];
  const int m0 = blockIdx.x*128, n0 = blockIdx.y*128;
  f32x4 acc[4][4] = {};
  gemm_tile_128(Ctx, WtO, As, Bs, m0, n0, acc);
  const int lane = threadIdx.x & 63;
  const int wid  = threadIdx.x >> 6;
  const int wrow = (wid >> 1) * 64, wcol = (wid & 1) * 64;
  const int l15 = lane & 15, lg = lane >> 4;
  #pragma unroll
  for (int i=0;i<4;++i)
    #pragma unroll
    for (int j=0;j<4;++j)
      #pragma unroll
      for (int r=0;r<4;++r){
        int m = m0 + wrow + 16*i + 4*lg + r;
        int n = n0 + wcol + 16*j + l15;
        out[m*EMBED + n] = acc[i][j][r] + bias[n];
      }
}

// --- causal flash attention v8: 8 waves/block, shared LDS K/V, 4 waves/SIMD -
// (unchanged from Round 8: 512 blocks x 8 waves; block = 128-row Q chunk;
// wave = 16 q rows; double-buffered K/V staging via global_load_lds with
// pre-swizzled source; swapped QK^T; in-lane softmax + defer-max; setprio.)
__global__ __launch_bounds__(512, 4) void attn_kernel(const short* __restrict__ Q,
    const short* __restrict__ K, const short* __restrict__ Vt, short* __restrict__ Ctx){
  __shared__ __align__(16) char lds[49152];   // K0 V0 | K1 V1 | P[8 waves]
  const int tid  = threadIdx.x;
  const int lane = tid & 63;
  const int wid  = tid >> 6;             // 0..7
  const int bid   = blockIdx.x;          // 0..511
  const int xcd   = bid & 7;
  const int i7    = bid >> 3;            // 0..63 (per-XCD order)
  const int bh    = xcd + 8*(i7 & 3);    // 4 heads per XCD
  const int cidx  = i7 >> 2;             // 0..15
  const int chunk = (cidx < 8) ? cidx : 23 - cidx;  // pair sums 15 -> equal work
  const int q0blk = chunk * 128;
  const int ntblk = 2*chunk + 2;         // kv tiles for this block
  const int q0w   = q0blk + 16*wid;      // this wave's first q row
  const int qlast = q0w + 15;

  const short* Qh  = Q  + bh*(SEQL*HDIM);
  const char*  KhB = (const char*)(K  + bh*(SEQL*HDIM));
  const char*  VhB = (const char*)(Vt + bh*(HDIM*SEQL));
  const int l15 = lane & 15, lg = lane >> 4;
  const int lg20 = 20 * lg;
  const int swE = (l15 & 7) << 3;        // P swizzle (elements)
  const int swB = (l15 & 7) << 4;        // K/V read swizzle (bytes)
  const int laneRow = lane >> 3;                       // 0..7
  const int colSwz  = 16 * ((lane & 7) ^ laneRow);     // inverse swizzle
  const int r0 = 8 * wid;                              // this wave's stage rows

  const short* qp = Qh + (q0w + l15)*HDIM + 8*lg;
  bf16x8 bq0 = *(const bf16x8*)qp;
  bf16x8 bq1 = *(const bf16x8*)(qp + 32);

  f32x4 acc[4];                          // [j]: rows q=4lg+r, cols d=16j+l15
  #pragma unroll
  for (int j=0; j<4; ++j) acc[j] = (f32x4){0.f,0.f,0.f,0.f};
  float mrun = -3e30f, lrun = 0.f;       // per lane: state of q-row l15

  short* pw = (short*)(lds + 32768 + wid*2048);  // per-wave 16x64 bf16 P

  auto STAGE = [&](int b, int t){
    char* kb = lds + b*16384;
    char* vb = kb + 8192;
    const int kv0 = t*64;
    GLDS(KhB + (kv0 + r0 + laneRow)*128 + colSwz, kb + r0*128);
    GLDS(VhB + (r0 + laneRow)*4096 + kv0*2 + colSwz, vb + r0*128);
  };

  STAGE(0, 0);
  __syncthreads();

  int cur = 0;
  for (int t = 0; t < ntblk; ++t){
    const int kv0 = t*64;
    if (t + 1 < ntblk) STAGE(cur ^ 1, t + 1);
    if (kv0 <= qlast){
      const char* kb = lds + cur*16384;
      const char* vb = kb + 8192;
      // S^T: sc[c] rows kv=16c+4lg+r, col q=l15 (K from LDS)
      f32x4 sc[4];
      __builtin_amdgcn_s_setprio(1);
      #pragma unroll
      for (int c=0; c<4; ++c){
        const char* kr = kb + (16*c + l15)*128;
        bf16x8 k0 = *(const bf16x8*)(kr + ((16*lg) ^ swB));
        bf16x8 k1 = *(const bf16x8*)(kr + ((64 + 16*lg) ^ swB));
        f32x4 z = (f32x4){0.f,0.f,0.f,0.f};
        z = __builtin_amdgcn_mfma_f32_16x16x32_bf16(k0, bq0, z, 0,0,0);
        z = __builtin_amdgcn_mfma_f32_16x16x32_bf16(k1, bq1, z, 0,0,0);
        sc[c] = z;
      }
      __builtin_amdgcn_s_setprio(0);
      // causal mask: kv = kv0+16c+4lg+r vs q = q0w+l15
      if (kv0 + 63 > q0w){
        #pragma unroll
        for (int c=0; c<4; ++c)
          #pragma unroll
          for (int r=0; r<4; ++r)
            if (kv0 + 16*c + 4*lg + r > q0w + l15) sc[c][r] = -3e30f;
      }
      // online softmax: in-lane over 16 + 2 shuffles; T13 defer-max
      float pm = -3e30f;
      #pragma unroll
      for (int c=0; c<4; ++c)
        #pragma unroll
        for (int r=0; r<4; ++r) pm = fmaxf(pm, sc[c][r]);
      pm = fmaxf(pm, __shfl_xor(pm, 16));
      pm = fmaxf(pm, __shfl_xor(pm, 32));
      const int resc = !__all(pm <= mrun);
      float mn = mrun, ss = 1.0f;
      if (resc){
        mn = fmaxf(mrun, pm);
        ss = __builtin_amdgcn_exp2f(mrun - mn);
        mrun = mn;
      }
      float ls = 0.f;
      #pragma unroll
      for (int c=0; c<4; ++c)
        #pragma unroll
        for (int r=0; r<4; ++r){
          float p = __builtin_amdgcn_exp2f(sc[c][r] - mn);
          sc[c][r] = p;
          ls += p;
        }
      ls += __shfl_xor(ls, 16);
      ls += __shfl_xor(ls, 32);
      if (resc){
        lrun = lrun*ss + ls;
        float srg[4];
        #pragma unroll
        for (int r=0; r<4; ++r) srg[r] = __shfl(ss, lg20 + r);
        #pragma unroll
        for (int j=0; j<4; ++j)
          #pragma unroll
          for (int r=0; r<4; ++r) acc[j][r] *= srg[r];
      } else {
        lrun += ls;
      }
      // P -> per-wave LDS (swizzled), read back as PV A-frags
      #pragma unroll
      for (int c=0; c<4; ++c){
        short4 pk;
        pk.x = f2bf(sc[c][0]); pk.y = f2bf(sc[c][1]);
        pk.z = f2bf(sc[c][2]); pk.w = f2bf(sc[c][3]);
        *(short4*)(pw + l15*64 + ((16*c + 4*lg) ^ swE)) = pk;
      }
      bf16x8 pa0 = *(const bf16x8*)(pw + l15*64 + ((8*lg)      ^ swE));
      bf16x8 pa1 = *(const bf16x8*)(pw + l15*64 + ((32 + 8*lg) ^ swE));
      // PV: acc[j] += P V  (V^T from LDS, rows = d)
      __builtin_amdgcn_s_setprio(1);
      #pragma unroll
      for (int j=0; j<4; ++j){
        const char* vrp = vb + (16*j + l15)*128;
        bf16x8 v0 = *(const bf16x8*)(vrp + ((16*lg) ^ swB));
        bf16x8 v1 = *(const bf16x8*)(vrp + ((64 + 16*lg) ^ swB));
        acc[j] = __builtin_amdgcn_mfma_f32_16x16x32_bf16(pa0, v0, acc[j], 0,0,0);
        acc[j] = __builtin_amdgcn_mfma_f32_16x16x32_bf16(pa1, v1, acc[j], 0,0,0);
      }
      __builtin_amdgcn_s_setprio(0);
    }
    __syncthreads();
    cur ^= 1;
  }

  // epilogue: redistribute lrun to acc rows, scale, write ctx
  const int bb = bh >> 4, hh = bh & 15;
  float lr[4];
  #pragma unroll
  for (int r=0; r<4; ++r) lr[r] = __builtin_amdgcn_rcpf(__shfl(lrun, lg20 + r));
  #pragma unroll
  for (int j=0; j<4; ++j)
    #pragma unroll
    for (int r=0; r<4; ++r){
      int qg = q0w + 4*lg + r;
      Ctx[(bb*SEQL + qg)*EMBED + hh*HDIM + 16*j + l15] = f2bf(acc[j][r] * lr[r]);
    }
}

extern "C" void kernel_launch(void* const* d_in, const int* in_sizes, int n_in,
                              void* d_out, int out_size, void* d_ws, size_t ws_size,
                              hipStream_t stream){
  const float* x  = (const float*)d_in[0];
  const float* Wq = (const float*)d_in[1];
  const float* Wk = (const float*)d_in[2];
  const float* Wv = (const float*)d_in[3];
  const float* Wo = (const float*)d_in[4];
  const float* bo = (const float*)d_in[5];
  float* out = (float*)d_out;

  char* ws = (char*)d_ws;
  const size_t MB = 1u << 20;
  short* Xb  = (short*)(ws +  0*MB);  // [4096][1024] bf16 (8 MB)
  short* Wt  = (short*)(ws +  8*MB);  // 4x [1024][1024] bf16 transposed (8 MB)
  short* Q   = (short*)(ws + 16*MB);  // [b,h,s,d] (8 MB)
  short* Kk  = (short*)(ws + 24*MB);  // [b,h,s,d] (8 MB)
  short* Vt  = (short*)(ws + 32*MB);  // [b,h,d,s] (8 MB)
  short* Ctx = (short*)(ws + 40*MB);  // [b,s,e]   (8 MB)

  cvt_kernel<<<4096, 256, 0, stream>>>(x, Xb, MROWS*EMBED);
  transpose_kernel<<<dim3(32,32,4), 256, 0, stream>>>(Wq, Wk, Wv, Wo, Wt);
  gemm_qkv_kernel<<<dim3(32,8,3), 256, 0, stream>>>(Xb, Wt, Q, Kk, Vt);
  attn_kernel<<<512, 512, 0, stream>>>(Q, Kk, Vt, Ctx);
  gemm_out_kernel<<<dim3(32,8), 256, 0, stream>>>(Ctx, Wt + 3*(EMBED*EMBED), bo, out);
}

// Round 10
// 112.227 us; speedup vs baseline: 2.2726x; 1.0082x over previous
//
#include <hip/hip_runtime.h>

#define EMBED 1024
#define SEQL  2048
#define NHEAD 16
#define HDIM  64
#define NBATCH 2
#define MROWS 4096   // NBATCH*SEQL

typedef __attribute__((ext_vector_type(4))) float  f32x4;
typedef __attribute__((ext_vector_type(8))) __bf16 bf16x8;

__device__ __forceinline__ short f2bf(float f){
  union { float f; unsigned u; } x; x.f = f;
  unsigned r = x.u + 0x7fffu + ((x.u >> 16) & 1u);
  return (short)(r >> 16);
}

#define GLDS(gp, lp) __builtin_amdgcn_global_load_lds( \
    (const __attribute__((address_space(1))) void*)(gp), \
    (__attribute__((address_space(3))) void*)(lp), 16, 0, 0)

// ---------------- fp32 -> bf16 convert (x) ----------------
__global__ __launch_bounds__(256) void cvt_kernel(const float* __restrict__ in,
                                                  short* __restrict__ out, int n){
  int i = (blockIdx.x * 256 + threadIdx.x) * 4;
  if (i >= n) return;
  float4 v = *(const float4*)(in + i);
  short4 o; o.x = f2bf(v.x); o.y = f2bf(v.y); o.z = f2bf(v.z); o.w = f2bf(v.w);
  *(short4*)(out + i) = o;
}

// ------- W [K][N] fp32 -> Wt [N][K] bf16, 4 matrices via blockIdx.z -------
__global__ __launch_bounds__(256) void transpose_kernel(const float* __restrict__ W0,
    const float* __restrict__ W1, const float* __restrict__ W2, const float* __restrict__ W3,
    short* __restrict__ WtAll){
  __shared__ float tile[32][33];
  const int z = blockIdx.z;
  const float* W = (z==0)?W0:(z==1)?W1:(z==2)?W2:W3;
  short* Wt = WtAll + z*(EMBED*EMBED);
  const int bx = blockIdx.x*32, by = blockIdx.y*32;
  const int tx = threadIdx.x & 31, ty = threadIdx.x >> 5;
  #pragma unroll
  for (int i=0;i<32;i+=8) tile[ty+i][tx] = W[(by+ty+i)*EMBED + bx+tx];
  __syncthreads();
  #pragma unroll
  for (int i=0;i<32;i+=8) Wt[(bx+ty+i)*EMBED + by+tx] = f2bf(tile[tx][ty+i]);
}

// -------- 128x128 bf16 GEMM mainloop, 2-phase double-buffered ---------------
__device__ __forceinline__ void gemm_tile_128(const short* __restrict__ A,
    const short* __restrict__ Bt, short* As, short* Bs, int m0, int n0, f32x4 acc[4][4]){
  const int tid  = threadIdx.x;
  const int lane = tid & 63;
  const int wid  = tid >> 6;
  const int wrow = (wid >> 1) * 64, wcol = (wid & 1) * 64;
  const int arow = tid >> 2, acol8 = (tid & 3) * 8;
  const int l15 = lane & 15, lg = lane >> 4;

  auto STAGE = [&](int b, int k0){
    short* as = As + b*4096;
    short* bs = Bs + b*4096;
    GLDS(A  + (m0      + arow) * 1024 + k0 + acol8, as + tid*8);
    GLDS(A  + (m0 + 64 + arow) * 1024 + k0 + acol8, as + 2048 + tid*8);
    GLDS(Bt + (n0      + arow) * 1024 + k0 + acol8, bs + tid*8);
    GLDS(Bt + (n0 + 64 + arow) * 1024 + k0 + acol8, bs + 2048 + tid*8);
  };

  STAGE(0, 0);
  __syncthreads();
  int cur = 0;
  for (int k0 = 0; k0 < 1024; k0 += 32){
    if (k0 + 32 < 1024) STAGE(cur ^ 1, k0 + 32);
    const short* as = As + cur*4096;
    const short* bs = Bs + cur*4096;
    bf16x8 a[4], b[4];
    #pragma unroll
    for (int i=0;i<4;++i) a[i] = *(const bf16x8*)(as + (wrow+16*i+l15)*32 + 8*lg);
    #pragma unroll
    for (int j=0;j<4;++j) b[j] = *(const bf16x8*)(bs + (wcol+16*j+l15)*32 + 8*lg);
    #pragma unroll
    for (int i=0;i<4;++i)
      #pragma unroll
      for (int j=0;j<4;++j)
        acc[i][j] = __builtin_amdgcn_mfma_f32_16x16x32_bf16(a[i], b[j], acc[i][j], 0,0,0);
    __syncthreads();
    cur ^= 1;
  }
}

// -------- 64x128 bf16 GEMM mainloop (BM=64, 4 waves, for out-GEMM) ----------
__device__ __forceinline__ void gemm_tile_64(const short* __restrict__ A,
    const short* __restrict__ Bt, short* As, short* Bs, int m0, int n0, f32x4 acc[2][4]){
  const int tid  = threadIdx.x;
  const int lane = tid & 63;
  const int wid  = tid >> 6;
  const int wrow = (wid >> 1) * 32, wcol = (wid & 1) * 64;
  const int arow = tid >> 2, acol8 = (tid & 3) * 8;
  const int l15 = lane & 15, lg = lane >> 4;

  auto STAGE = [&](int b, int k0){
    short* as = As + b*2048;
    short* bs = Bs + b*4096;
    GLDS(A  + (m0      + arow) * 1024 + k0 + acol8, as + tid*8);
    GLDS(Bt + (n0      + arow) * 1024 + k0 + acol8, bs + tid*8);
    GLDS(Bt + (n0 + 64 + arow) * 1024 + k0 + acol8, bs + 2048 + tid*8);
  };

  STAGE(0, 0);
  __syncthreads();
  int cur = 0;
  for (int k0 = 0; k0 < 1024; k0 += 32){
    if (k0 + 32 < 1024) STAGE(cur ^ 1, k0 + 32);
    const short* as = As + cur*2048;
    const short* bs = Bs + cur*4096;
    bf16x8 a[2], b[4];
    #pragma unroll
    for (int i=0;i<2;++i) a[i] = *(const bf16x8*)(as + (wrow+16*i+l15)*32 + 8*lg);
    #pragma unroll
    for (int j=0;j<4;++j) b[j] = *(const bf16x8*)(bs + (wcol+16*j+l15)*32 + 8*lg);
    #pragma unroll
    for (int i=0;i<2;++i)
      #pragma unroll
      for (int j=0;j<4;++j)
        acc[i][j] = __builtin_amdgcn_mfma_f32_16x16x32_bf16(a[i], b[j], acc[i][j], 0,0,0);
    __syncthreads();
    cur ^= 1;
  }
}

// QKV projections: z=0 -> Q [b,h,s,d] (pre-scaled), z=1 -> K, z=2 -> V^T [b,h,d,s]
// z==2 uses an LDS-transpose epilogue (coalesced V^T stores) reusing the
// 32 KB staging LDS; z<2 write near-coalesced 32B runs directly.
__global__ __launch_bounds__(256) void gemm_qkv_kernel(const short* __restrict__ Xb,
    const short* __restrict__ WtAll, short* __restrict__ Q, short* __restrict__ K,
    short* __restrict__ Vt){
  __shared__ __align__(16) short SH[16384];   // As: SH[0..8191], Bs: SH[8192..]
  short* As = SH;
  short* Bs = SH + 8192;
  const int m0 = blockIdx.x*128, n0 = blockIdx.y*128, z = blockIdx.z;
  const short* Bt = WtAll + z*(EMBED*EMBED);
  f32x4 acc[4][4] = {};
  gemm_tile_128(Xb, Bt, As, Bs, m0, n0, acc);
  const int tid  = threadIdx.x;
  const int lane = tid & 63;
  const int wid  = tid >> 6;
  const int wrow = (wid >> 1) * 64, wcol = (wid & 1) * 64;
  const int l15 = lane & 15, lg = lane >> 4;
  const int bb = m0 >> 11, srow0 = m0 & 2047;

  if (z < 2){
    short* out = z ? K : Q;
    const float qscl = (z==0) ? (0.125f * 1.44269504f) : 1.0f;
    #pragma unroll
    for (int i=0;i<4;++i)
      #pragma unroll
      for (int j=0;j<4;++j)
        #pragma unroll
        for (int r=0;r<4;++r){
          int m = m0 + wrow + 16*i + 4*lg + r;
          int n = n0 + wcol + 16*j + l15;
          int srow = m & 2047, hh = n >> 6, d = n & 63;
          out[(((bb<<4)+hh)*SEQL + srow)*HDIM + d] = f2bf(acc[i][j][r] * qscl);
        }
  } else {
    // LDS transpose: T[n_loc][m_loc] bf16 (128x128 = 32 KB), m XOR-swizzled
    short* T = SH;                       // mainloop ended with __syncthreads
    #pragma unroll
    for (int i=0;i<4;++i)
      #pragma unroll
      for (int j=0;j<4;++j){
        int n_loc = wcol + 16*j + l15;
        int mb    = wrow + 16*i + 4*lg;   // multiple of 4
        short4 pk;
        pk.x = f2bf(acc[i][j][0]); pk.y = f2bf(acc[i][j][1]);
        pk.z = f2bf(acc[i][j][2]); pk.w = f2bf(acc[i][j][3]);
        *(short4*)(T + n_loc*128 + (mb ^ ((n_loc & 7) << 3))) = pk;
      }
    __syncthreads();
    // coalesced readout: 8 iters x 256 thr x 8 shorts = 16384
    #pragma unroll
    for (int it=0; it<8; ++it){
      int n_loc = 16*it + (tid >> 4);
      int mch   = (tid & 15) * 8;
      int4 v = *(const int4*)(T + n_loc*128 + (mch ^ ((n_loc & 7) << 3)));
      int n_glob = n0 + n_loc;
      int hh = n_glob >> 6, d = n_glob & 63;
      *(int4*)(Vt + (((bb<<4)+hh)*HDIM + d)*SEQL + srow0 + mch) = v;
    }
  }
}

// Output projection: out = Ctx @ W_o + b_o (fp32), BM=64 for 2x occupancy
__global__ __launch_bounds__(256) void gemm_out_kernel(const short* __restrict__ Ctx,
    const short* __restrict__ WtO, const float* __restrict__ bias, float* __restrict__ out){
  __shared__ __align__(16) short As[2*2048], Bs[2*4096];
  const int m0 = blockIdx.x*64, n0 = blockIdx.y*128;
  f32x4 acc[2][4] = {};
  gemm_tile_64(Ctx, WtO, As, Bs, m0, n0, acc);
  const int lane = threadIdx.x & 63;
  const int wid  = threadIdx.x >> 6;
  const int wrow = (wid >> 1) * 32, wcol = (wid & 1) * 64;
  const int l15 = lane & 15, lg = lane >> 4;
  #pragma unroll
  for (int i=0;i<2;++i)
    #pragma unroll
    for (int j=0;j<4;++j)
      #pragma unroll
      for (int r=0;r<4;++r){
        int m = m0 + wrow + 16*i + 4*lg + r;
        int n = n0 + wcol + 16*j + l15;
        out[m*EMBED + n] = acc[i][j][r] + bias[n];
      }
}

// --- causal flash attention v8 (unchanged from Round 8) ---------------------
__global__ __launch_bounds__(512, 4) void attn_kernel(const short* __restrict__ Q,
    const short* __restrict__ K, const short* __restrict__ Vt, short* __restrict__ Ctx){
  __shared__ __align__(16) char lds[49152];   // K0 V0 | K1 V1 | P[8 waves]
  const int tid  = threadIdx.x;
  const int lane = tid & 63;
  const int wid  = tid >> 6;             // 0..7
  const int bid   = blockIdx.x;          // 0..511
  const int xcd   = bid & 7;
  const int i7    = bid >> 3;            // 0..63 (per-XCD order)
  const int bh    = xcd + 8*(i7 & 3);    // 4 heads per XCD
  const int cidx  = i7 >> 2;             // 0..15
  const int chunk = (cidx < 8) ? cidx : 23 - cidx;  // pair sums 15 -> equal work
  const int q0blk = chunk * 128;
  const int ntblk = 2*chunk + 2;         // kv tiles for this block
  const int q0w   = q0blk + 16*wid;      // this wave's first q row
  const int qlast = q0w + 15;

  const short* Qh  = Q  + bh*(SEQL*HDIM);
  const char*  KhB = (const char*)(K  + bh*(SEQL*HDIM));
  const char*  VhB = (const char*)(Vt + bh*(HDIM*SEQL));
  const int l15 = lane & 15, lg = lane >> 4;
  const int lg20 = 20 * lg;
  const int swE = (l15 & 7) << 3;        // P swizzle (elements)
  const int swB = (l15 & 7) << 4;        // K/V read swizzle (bytes)
  const int laneRow = lane >> 3;                       // 0..7
  const int colSwz  = 16 * ((lane & 7) ^ laneRow);     // inverse swizzle
  const int r0 = 8 * wid;                              // this wave's stage rows

  const short* qp = Qh + (q0w + l15)*HDIM + 8*lg;
  bf16x8 bq0 = *(const bf16x8*)qp;
  bf16x8 bq1 = *(const bf16x8*)(qp + 32);

  f32x4 acc[4];                          // [j]: rows q=4lg+r, cols d=16j+l15
  #pragma unroll
  for (int j=0; j<4; ++j) acc[j] = (f32x4){0.f,0.f,0.f,0.f};
  float mrun = -3e30f, lrun = 0.f;       // per lane: state of q-row l15

  short* pw = (short*)(lds + 32768 + wid*2048);  // per-wave 16x64 bf16 P

  auto STAGE = [&](int b, int t){
    char* kb = lds + b*16384;
    char* vb = kb + 8192;
    const int kv0 = t*64;
    GLDS(KhB + (kv0 + r0 + laneRow)*128 + colSwz, kb + r0*128);
    GLDS(VhB + (r0 + laneRow)*4096 + kv0*2 + colSwz, vb + r0*128);
  };

  STAGE(0, 0);
  __syncthreads();

  int cur = 0;
  for (int t = 0; t < ntblk; ++t){
    const int kv0 = t*64;
    if (t + 1 < ntblk) STAGE(cur ^ 1, t + 1);
    if (kv0 <= qlast){
      const char* kb = lds + cur*16384;
      const char* vb = kb + 8192;
      // S^T: sc[c] rows kv=16c+4lg+r, col q=l15 (K from LDS)
      f32x4 sc[4];
      __builtin_amdgcn_s_setprio(1);
      #pragma unroll
      for (int c=0; c<4; ++c){
        const char* kr = kb + (16*c + l15)*128;
        bf16x8 k0 = *(const bf16x8*)(kr + ((16*lg) ^ swB));
        bf16x8 k1 = *(const bf16x8*)(kr + ((64 + 16*lg) ^ swB));
        f32x4 z = (f32x4){0.f,0.f,0.f,0.f};
        z = __builtin_amdgcn_mfma_f32_16x16x32_bf16(k0, bq0, z, 0,0,0);
        z = __builtin_amdgcn_mfma_f32_16x16x32_bf16(k1, bq1, z, 0,0,0);
        sc[c] = z;
      }
      __builtin_amdgcn_s_setprio(0);
      // causal mask: kv = kv0+16c+4lg+r vs q = q0w+l15
      if (kv0 + 63 > q0w){
        #pragma unroll
        for (int c=0; c<4; ++c)
          #pragma unroll
          for (int r=0; r<4; ++r)
            if (kv0 + 16*c + 4*lg + r > q0w + l15) sc[c][r] = -3e30f;
      }
      // online softmax: in-lane over 16 + 2 shuffles; T13 defer-max
      float pm = -3e30f;
      #pragma unroll
      for (int c=0; c<4; ++c)
        #pragma unroll
        for (int r=0; r<4; ++r) pm = fmaxf(pm, sc[c][r]);
      pm = fmaxf(pm, __shfl_xor(pm, 16));
      pm = fmaxf(pm, __shfl_xor(pm, 32));
      const int resc = !__all(pm <= mrun);
      float mn = mrun, ss = 1.0f;
      if (resc){
        mn = fmaxf(mrun, pm);
        ss = __builtin_amdgcn_exp2f(mrun - mn);
        mrun = mn;
      }
      float ls = 0.f;
      #pragma unroll
      for (int c=0; c<4; ++c)
        #pragma unroll
        for (int r=0; r<4; ++r){
          float p = __builtin_amdgcn_exp2f(sc[c][r] - mn);
          sc[c][r] = p;
          ls += p;
        }
      ls += __shfl_xor(ls, 16);
      ls += __shfl_xor(ls, 32);
      if (resc){
        lrun = lrun*ss + ls;
        float srg[4];
        #pragma unroll
        for (int r=0; r<4; ++r) srg[r] = __shfl(ss, lg20 + r);
        #pragma unroll
        for (int j=0; j<4; ++j)
          #pragma unroll
          for (int r=0; r<4; ++r) acc[j][r] *= srg[r];
      } else {
        lrun += ls;
      }
      // P -> per-wave LDS (swizzled), read back as PV A-frags
      #pragma unroll
      for (int c=0; c<4; ++c){
        short4 pk;
        pk.x = f2bf(sc[c][0]); pk.y = f2bf(sc[c][1]);
        pk.z = f2bf(sc[c][2]); pk.w = f2bf(sc[c][3]);
        *(short4*)(pw + l15*64 + ((16*c + 4*lg) ^ swE)) = pk;
      }
      bf16x8 pa0 = *(const bf16x8*)(pw + l15*64 + ((8*lg)      ^ swE));
      bf16x8 pa1 = *(const bf16x8*)(pw + l15*64 + ((32 + 8*lg) ^ swE));
      // PV: acc[j] += P V  (V^T from LDS, rows = d)
      __builtin_amdgcn_s_setprio(1);
      #pragma unroll
      for (int j=0; j<4; ++j){
        const char* vrp = vb + (16*j + l15)*128;
        bf16x8 v0 = *(const bf16x8*)(vrp + ((16*lg) ^ swB));
        bf16x8 v1 = *(const bf16x8*)(vrp + ((64 + 16*lg) ^ swB));
        acc[j] = __builtin_amdgcn_mfma_f32_16x16x32_bf16(pa0, v0, acc[j], 0,0,0);
        acc[j] = __builtin_amdgcn_mfma_f32_16x16x32_bf16(pa1, v1, acc[j], 0,0,0);
      }
      __builtin_amdgcn_s_setprio(0);
    }
    __syncthreads();
    cur ^= 1;
  }

  // epilogue: redistribute lrun to acc rows, scale, write ctx
  const int bb = bh >> 4, hh = bh & 15;
  float lr[4];
  #pragma unroll
  for (int r=0; r<4; ++r) lr[r] = __builtin_amdgcn_rcpf(__shfl(lrun, lg20 + r));
  #pragma unroll
  for (int j=0; j<4; ++j)
    #pragma unroll
    for (int r=0; r<4; ++r){
      int qg = q0w + 4*lg + r;
      Ctx[(bb*SEQL + qg)*EMBED + hh*HDIM + 16*j + l15] = f2bf(acc[j][r] * lr[r]);
    }
}

extern "C" void kernel_launch(void* const* d_in, const int* in_sizes, int n_in,
                              void* d_out, int out_size, void* d_ws, size_t ws_size,
                              hipStream_t stream){
  const float* x  = (const float*)d_in[0];
  const float* Wq = (const float*)d_in[1];
  const float* Wk = (const float*)d_in[2];
  const float* Wv = (const float*)d_in[3];
  const float* Wo = (const float*)d_in[4];
  const float* bo = (const float*)d_in[5];
  float* out = (float*)d_out;

  char* ws = (char*)d_ws;
  const size_t MB = 1u << 20;
  short* Xb  = (short*)(ws +  0*MB);  // [4096][1024] bf16 (8 MB)
  short* Wt  = (short*)(ws +  8*MB);  // 4x [1024][1024] bf16 transposed (8 MB)
  short* Q   = (short*)(ws + 16*MB);  // [b,h,s,d] (8 MB)
  short* Kk  = (short*)(ws + 24*MB);  // [b,h,s,d] (8 MB)
  short* Vt  = (short*)(ws + 32*MB);  // [b,h,d,s] (8 MB)
  short* Ctx = (short*)(ws + 40*MB);  // [b,s,e]   (8 MB)

  cvt_kernel<<<4096, 256, 0, stream>>>(x, Xb, MROWS*EMBED);
  transpose_kernel<<<dim3(32,32,4), 256, 0, stream>>>(Wq, Wk, Wv, Wo, Wt);
  gemm_qkv_kernel<<<dim3(32,8,3), 256, 0, stream>>>(Xb, Wt, Q, Kk, Vt);
  attn_kernel<<<512, 512, 0, stream>>>(Q, Kk, Vt, Ctx);
  gemm_out_kernel<<<dim3(64,8), 256, 0, stream>>>(Ctx, Wt + 3*(EMBED*EMBED), bo, out);
}